// Round 8
// baseline (239.214 us; speedup 1.0000x reference)
//
#include <hip/hip_runtime.h>

#define N_NODES 50000
#define N_EDGES 800000
#define NBATCH 32
#define HWDIM 128
#define IMG (HWDIM * HWDIM)
#define HID 128
#define NBKT ((N_NODES + 255) / 256)  // 196 buckets of 256 dst nodes
#define NB 625                        // partition blocks
#define EPB 1280                      // edges per partition block
#define LDSP 40  // sage gemm LDS row stride (bf16)

typedef float f32x4 __attribute__((ext_vector_type(4)));
typedef __bf16 bf16x8 __attribute__((ext_vector_type(8)));
typedef unsigned short u16x8 __attribute__((ext_vector_type(8)));

__device__ __forceinline__ unsigned short f2bf(float x) {
  unsigned u = __builtin_bit_cast(unsigned, x);
  u = (u + 0x7FFF + ((u >> 16) & 1)) >> 16;
  return (unsigned short)u;
}
__device__ __forceinline__ float bf2f(unsigned short h) {
  return __builtin_bit_cast(float, (unsigned)h << 16);
}

// ---------------------------------------------------------------------------
// One merged weight-pack kernel:
//   [0, 32768)          -> Wb2[j][k] from Wl2/Wr2
//   [32768, 65536)      -> Wb3 from Wl3/Wr3
//   [65536, 67072)      -> Wc1 (conv1, CIN=8,  1536 elems)
//   [67072, 69632)      -> Wc2 (conv2, CIN=16, 2560 elems)
// ---------------------------------------------------------------------------
__global__ void pack_all_kernel(const float* __restrict__ Wl2, const float* __restrict__ Wr2,
                                const float* __restrict__ Wl3, const float* __restrict__ Wr3,
                                const float* __restrict__ w1, const float* __restrict__ w2,
                                unsigned short* __restrict__ Wb2, unsigned short* __restrict__ Wb3,
                                unsigned short* __restrict__ Wc1, unsigned short* __restrict__ Wc2) {
  int t = blockIdx.x * blockDim.x + threadIdx.x;
  if (t < 65536) {
    const float* Wl = (t < 32768) ? Wl2 : Wl3;
    const float* Wr = (t < 32768) ? Wr2 : Wr3;
    unsigned short* Wb = (t < 32768) ? Wb2 : Wb3;
    int tt = t & 32767;
    int j = tt >> 8, k = tt & 255;
    float v = (k < 128) ? Wl[j * 128 + k] : Wr[j * 128 + (k - 128)];
    Wb[tt] = f2bf(v);
    return;
  }
  int t2 = t - 65536;
  const float* w;
  unsigned short* dst;
  int CIN, idx;
  if (t2 < 1536) {
    w = w1; dst = Wc1; CIN = 8; idx = t2;
  } else if (t2 < 1536 + 2560) {
    w = w2; dst = Wc2; CIN = 16; idx = t2 - 1536;
  } else {
    return;
  }
  int j = idx & 7;
  int n = (idx >> 3) & 15;
  int sgi = idx >> 7;
  int k = sgi * 8 + j;
  int tap = k / CIN;
  int ci = k % CIN;
  dst[idx] = (tap < 9) ? f2bf(w[(n * CIN + ci) * 9 + tap]) : (unsigned short)0;
}

// ---------------------------------------------------------------------------
// MFMA conv1: CIN=8 (f32 NCHW input), COUT=16, relu, out NHWC bf16.
// ---------------------------------------------------------------------------
__global__ __launch_bounds__(256) void conv1_mfma_kernel(
    const float* __restrict__ in, const unsigned short* __restrict__ Wc,
    const float* __restrict__ bias, unsigned short* __restrict__ out) {
  __shared__ unsigned short lds[10 * 130 * 8];
  int tid = threadIdx.x;
  int img = blockIdx.x >> 4;
  int y0 = (blockIdx.x & 15) * 8;
  int lane = tid & 63, wave = tid >> 6;
  int l15 = lane & 15, g = lane >> 4;

  const float* sb = in + (size_t)img * 8 * IMG;
#pragma unroll
  for (int i = 0; i < 5; ++i) {
    int idx = tid + i * 256;
    int r = idx >> 7;
    int x = idx & 127;
    int gy = y0 - 1 + r;
    u16x8 v = {};
    if ((unsigned)gy < (unsigned)HWDIM) {
      const float* sp = sb + gy * HWDIM + x;
#pragma unroll
      for (int ci = 0; ci < 8; ++ci) v[ci] = f2bf(sp[ci * IMG]);
    }
    *(u16x8*)&lds[(r * 130 + x + 1) * 8] = v;
  }
  if (tid < 20) {
    int r = tid >> 1, c = (tid & 1) * 129;
    *(u16x8*)&lds[(r * 130 + c) * 8] = (u16x8){};
  }

  bf16x8 bfrag[3];
  int adel[3];
#pragma unroll
  for (int s = 0; s < 3; ++s) {
    bfrag[s] = __builtin_bit_cast(bf16x8, *(const u16x8*)(Wc + (((s * 4 + g) * 16) + l15) * 8));
    int tap = (32 * s + 8 * g) / 8;
    tap = tap > 8 ? 8 : tap;
    adel[s] = ((tap / 3) * 130 + (tap % 3)) * 8;
  }
  float bv = bias[l15];
  __syncthreads();

#pragma unroll
  for (int ti = 0; ti < 16; ++ti) {
    int tile = wave * 16 + ti;
    int ly = tile >> 3, xb = (tile & 7) * 16;
    int tb = (ly * 130 + xb + l15) * 8;
    f32x4 acc = {};
#pragma unroll
    for (int s = 0; s < 3; ++s) {
      bf16x8 a = __builtin_bit_cast(bf16x8, *(const u16x8*)&lds[tb + adel[s]]);
      acc = __builtin_amdgcn_mfma_f32_16x16x32_bf16(a, bfrag[s], acc, 0, 0, 0);
    }
    size_t base = (((size_t)img * HWDIM + y0 + ly) * HWDIM + xb);
#pragma unroll
    for (int r = 0; r < 4; ++r) {
      float v = fmaxf(acc[r] + bv, 0.0f);
      out[(base + g * 4 + r) * 16 + l15] = f2bf(v);
    }
  }
}

// ---------------------------------------------------------------------------
// MFMA conv2: CIN=16 (NHWC bf16 input), COUT=16, relu, out NHWC bf16.
// ---------------------------------------------------------------------------
__global__ __launch_bounds__(256) void conv2_mfma_kernel(
    const unsigned short* __restrict__ in, const unsigned short* __restrict__ Wc,
    const float* __restrict__ bias, unsigned short* __restrict__ out) {
  __shared__ unsigned short lds[10 * 130 * 24];
  int tid = threadIdx.x;
  int img = blockIdx.x >> 4;
  int y0 = (blockIdx.x & 15) * 8;
  int lane = tid & 63, wave = tid >> 6;
  int l15 = lane & 15, g = lane >> 4;

  const unsigned short* sb = in + (size_t)img * IMG * 16;
#pragma unroll
  for (int i = 0; i < 10; ++i) {
    int idx = tid + i * 256;
    int r = idx >> 8;
    int x = (idx & 255) >> 1;
    int hh = idx & 1;
    int gy = y0 - 1 + r;
    u16x8 v = {};
    if ((unsigned)gy < (unsigned)HWDIM) v = *(const u16x8*)(sb + ((size_t)gy * HWDIM + x) * 16 + hh * 8);
    *(u16x8*)&lds[(r * 130 + x + 1) * 24 + hh * 8] = v;
  }
  if (tid < 20) {
    int r = tid >> 1, c = (tid & 1) * 129;
#pragma unroll
    for (int q = 0; q < 3; ++q) *(u16x8*)&lds[(r * 130 + c) * 24 + q * 8] = (u16x8){};
  }

  bf16x8 bfrag[5];
  int adel[5];
#pragma unroll
  for (int s = 0; s < 5; ++s) {
    bfrag[s] = __builtin_bit_cast(bf16x8, *(const u16x8*)(Wc + (((s * 4 + g) * 16) + l15) * 8));
    int tap = (32 * s + 8 * g) / 16;
    tap = tap > 8 ? 8 : tap;
    adel[s] = ((tap / 3) * 130 + (tap % 3)) * 24 + (g & 1) * 8;
  }
  float bv = bias[l15];
  __syncthreads();

#pragma unroll
  for (int ti = 0; ti < 16; ++ti) {
    int tile = wave * 16 + ti;
    int ly = tile >> 3, xb = (tile & 7) * 16;
    int tb = (ly * 130 + xb + l15) * 24;
    f32x4 acc = {};
#pragma unroll
    for (int s = 0; s < 5; ++s) {
      bf16x8 a = __builtin_bit_cast(bf16x8, *(const u16x8*)&lds[tb + adel[s]]);
      acc = __builtin_amdgcn_mfma_f32_16x16x32_bf16(a, bfrag[s], acc, 0, 0, 0);
    }
    size_t base = (((size_t)img * HWDIM + y0 + ly) * HWDIM + xb);
#pragma unroll
    for (int r = 0; r < 4; ++r) {
      float v = fmaxf(acc[r] + bv, 0.0f);
      out[(base + g * 4 + r) * 16 + l15] = f2bf(v);
    }
  }
}

// ---------------------------------------------------------------------------
// conv3: CIN=16 (NHWC bf16), COUT=1, no relu, f32 NCHW out. 1 px/thread.
// ---------------------------------------------------------------------------
__global__ __launch_bounds__(256) void conv3_f32_kernel(const unsigned short* __restrict__ h2,
                                                        const float* __restrict__ w3,
                                                        const float* __restrict__ b3,
                                                        float* __restrict__ x1) {
  __shared__ float w9[9][16];
  __shared__ float b3s;
  int tid = threadIdx.x;
  if (tid < 144) {
    int ci = tid & 15, tap = tid >> 4;
    w9[tap][ci] = w3[ci * 9 + tap];
  }
  if (tid == 144) b3s = b3[0];
  __syncthreads();
  int t = blockIdx.x * 256 + tid;
  int x = t & 127;
  int y = (t >> 7) & 127;
  int img = t >> 14;
  float acc = b3s;
#pragma unroll
  for (int dy = 0; dy < 3; ++dy) {
    int yy = y + dy - 1;
    if ((unsigned)yy >= (unsigned)HWDIM) continue;
#pragma unroll
    for (int dx = 0; dx < 3; ++dx) {
      int xx = x + dx - 1;
      if ((unsigned)xx >= (unsigned)HWDIM) continue;
      const u16x8* p = (const u16x8*)(h2 + (((size_t)img * HWDIM + yy) * HWDIM + xx) * 16);
      u16x8 lo = p[0], hi = p[1];
      const float* wt = w9[dy * 3 + dx];
#pragma unroll
      for (int j = 0; j < 8; ++j) acc += bf2f(lo[j]) * wt[j];
#pragma unroll
      for (int j = 0; j < 8; ++j) acc += bf2f(hi[j]) * wt[8 + j];
    }
  }
  x1[(size_t)img * IMG + y * HWDIM + x] = acc;
}

// ---------------------------------------------------------------------------
// Atomic-free bucketed CSR build (counting sort by 256-node buckets).
// ---------------------------------------------------------------------------
__global__ __launch_bounds__(256) void count_kernel(const int* __restrict__ ei,
                                                    int* __restrict__ cnt_mat) {
  __shared__ int hist[NBKT];
  int t = threadIdx.x;
  if (t < NBKT) hist[t] = 0;
  __syncthreads();
  int e0 = blockIdx.x * EPB;
#pragma unroll
  for (int i = 0; i < EPB / 256; ++i) {
    int d = ei[N_EDGES + e0 + i * 256 + t];
    atomicAdd(&hist[d >> 8], 1);
  }
  __syncthreads();
  if (t < NBKT) cnt_mat[t * NB + blockIdx.x] = hist[t];
}

__global__ __launch_bounds__(1024) void scan_rows_kernel(const int* __restrict__ cnt_mat,
                                                         int* __restrict__ rowscan,
                                                         int* __restrict__ row_total) {
  __shared__ int wsum[16];
  int row = blockIdx.x;
  int t = threadIdx.x;
  int lane = t & 63, w = t >> 6;
  int v = (t < NB) ? cnt_mat[row * NB + t] : 0;
  int s = v;
#pragma unroll
  for (int off = 1; off < 64; off <<= 1) {
    int u = __shfl_up(s, off, 64);
    if (lane >= off) s += u;
  }
  if (lane == 63) wsum[w] = s;
  __syncthreads();
  if (w == 0 && lane < 16) {
    int ws = wsum[lane];
#pragma unroll
    for (int off = 1; off < 16; off <<= 1) {
      int u = __shfl_up(ws, off, 64);
      if (lane >= off) ws += u;
    }
    wsum[lane] = ws;
  }
  __syncthreads();
  int base = (w > 0) ? wsum[w - 1] : 0;
  int incl = s + base;
  if (t < NB) rowscan[row * NB + t] = incl - v;
  if (t == NB - 1) row_total[row] = incl;
}

__global__ __launch_bounds__(256) void scan_roots_kernel(const int* __restrict__ row_total,
                                                         int* __restrict__ bucket_base,
                                                         int* __restrict__ row_ptr) {
  __shared__ int wsum[4];
  int t = threadIdx.x;
  int lane = t & 63, w = t >> 6;
  int v = (t < NBKT) ? row_total[t] : 0;
  int s = v;
#pragma unroll
  for (int off = 1; off < 64; off <<= 1) {
    int u = __shfl_up(s, off, 64);
    if (lane >= off) s += u;
  }
  if (lane == 63) wsum[w] = s;
  __syncthreads();
  int add = 0;
#pragma unroll
  for (int i = 0; i < 4; ++i)
    if (i < w) add += wsum[i];
  if (t < NBKT) bucket_base[t] = s + add - v;
  if (t == 0) row_ptr[N_NODES] = N_EDGES;
}

__global__ __launch_bounds__(256) void scatter2_kernel(const int* __restrict__ ei,
                                                       const int* __restrict__ rowscan,
                                                       const int* __restrict__ bucket_base,
                                                       int* __restrict__ bucket_data) {
  __shared__ int lhist[NBKT];
  __shared__ int lexcl[NBKT];
  __shared__ int gb[NBKT];
  __shared__ int wsum[4];
  __shared__ int lds_pack[EPB];
  __shared__ int lds_dest[EPB];
  int t = threadIdx.x;
  int blk = blockIdx.x;
  if (t < NBKT) lhist[t] = 0;
  __syncthreads();
  int e0 = blk * EPB;
  int myb[EPB / 256], myp[EPB / 256], mypack[EPB / 256];
#pragma unroll
  for (int i = 0; i < EPB / 256; ++i) {
    int e = e0 + i * 256 + t;
    int s = ei[e];
    int d = ei[N_EDGES + e];
    int b = d >> 8;
    myb[i] = b;
    mypack[i] = s | ((d & 255) << 16);
    myp[i] = atomicAdd(&lhist[b], 1);
  }
  __syncthreads();
  {
    int lane = t & 63, w = t >> 6;
    int v = (t < NBKT) ? lhist[t] : 0;
    int s = v;
#pragma unroll
    for (int off = 1; off < 64; off <<= 1) {
      int u = __shfl_up(s, off, 64);
      if (lane >= off) s += u;
    }
    if (lane == 63) wsum[w] = s;
    __syncthreads();
    int add = 0;
#pragma unroll
    for (int i = 0; i < 4; ++i)
      if (i < w) add += wsum[i];
    if (t < NBKT) {
      lexcl[t] = s + add - v;
      gb[t] = bucket_base[t] + rowscan[t * NB + blk];
    }
  }
  __syncthreads();
#pragma unroll
  for (int i = 0; i < EPB / 256; ++i) {
    int slot = lexcl[myb[i]] + myp[i];
    lds_pack[slot] = mypack[i];
    lds_dest[slot] = gb[myb[i]] + myp[i];
  }
  __syncthreads();
#pragma unroll
  for (int i = 0; i < EPB / 256; ++i) {
    int slot = i * 256 + t;
    bucket_data[lds_dest[slot]] = lds_pack[slot];
  }
}

__global__ __launch_bounds__(256) void bucketB_kernel(const int* __restrict__ row_total,
                                                      const int* __restrict__ bucket_base,
                                                      const int* __restrict__ bucket_data,
                                                      int* __restrict__ row_ptr,
                                                      int* __restrict__ csr) {
  __shared__ int cnts[256];
  __shared__ int curs[256];
  __shared__ int wsum[4];
  int b = blockIdx.x;
  int t = threadIdx.x;
  int cnt = row_total[b];
  int base = bucket_base[b];
  cnts[t] = 0;
  __syncthreads();
  const int* bd = bucket_data + base;
  for (int k = t; k < cnt; k += 256) {
    int v = bd[k];
    atomicAdd(&cnts[(v >> 16) & 255], 1);
  }
  __syncthreads();
  int v = cnts[t];
  int lane = t & 63, w = t >> 6;
  int s = v;
#pragma unroll
  for (int off = 1; off < 64; off <<= 1) {
    int u = __shfl_up(s, off, 64);
    if (lane >= off) s += u;
  }
  if (lane == 63) wsum[w] = s;
  __syncthreads();
  int add = 0;
#pragma unroll
  for (int i = 0; i < 4; ++i)
    if (i < w) add += wsum[i];
  int excl = s + add - v;
  int node = b * 256 + t;
  if (node < N_NODES) row_ptr[node] = base + excl;
  curs[t] = excl;
  __syncthreads();
  for (int k = t; k < cnt; k += 256) {
    int vv = bd[k];
    int p = atomicAdd(&curs[(vv >> 16) & 255], 1);
    csr[base + p] = vv & 0xffff;
  }
}

// ---------------------------------------------------------------------------
// gather node features: gx = [x0, x1, x5, x6, x7, pos0, pos1, cnng]
// ---------------------------------------------------------------------------
__global__ void gather_gx_kernel(const float* __restrict__ x, const float* __restrict__ pos,
                                 const int* __restrict__ batch, const float* __restrict__ x1,
                                 float* __restrict__ gx) {
  int t = blockIdx.x * blockDim.x + threadIdx.x;
  if (t >= N_NODES) return;
  float px = pos[2 * t + 0];
  float py = pos[2 * t + 1];
  float fx = px / 20.0f * 127.0f;
  float fy = py / 20.0f * 127.0f;
  int cx = (int)rintf(fx);
  int cy = (int)rintf(fy);
  cx = min(max(cx, 0), HWDIM - 1);
  cy = min(max(cy, 0), HWDIM - 1);
  int b = batch[t];
  float cn = x1[(size_t)b * IMG + cy * HWDIM + cx];
  const float* xr = x + (size_t)t * 8;
  float* g = gx + (size_t)t * 8;
  g[0] = xr[0];
  g[1] = xr[1];
  g[2] = xr[5];
  g[3] = xr[6];
  g[4] = xr[7];
  g[5] = px;
  g[6] = py;
  g[7] = cn;
}

// ---------------------------------------------------------------------------
// CSR aggregation, C=8 (f32 in/out)
// ---------------------------------------------------------------------------
__global__ void agg8_kernel(const float* __restrict__ gx, const int* __restrict__ row_ptr,
                            const int* __restrict__ csr, float* __restrict__ out) {
  int t = blockIdx.x * blockDim.x + threadIdx.x;
  int i = t >> 3;
  int f = t & 7;
  if (i >= N_NODES) return;
  int beg = row_ptr[i], end = row_ptr[i + 1];
  float acc = 0.0f;
  int k = beg;
  for (; k + 2 <= end; k += 2) {
    int s0 = csr[k], s1 = csr[k + 1];
    acc += gx[(size_t)s0 * 8 + f] + gx[(size_t)s1 * 8 + f];
  }
  for (; k < end; ++k) acc += gx[(size_t)csr[k] * 8 + f];
  out[(size_t)i * 8 + f] = acc / fmaxf((float)(end - beg), 1.0f);
}

// ---------------------------------------------------------------------------
// CSR aggregation, C=128, bf16 in/out, f32 accum.
// One wave per node; TWO rows per vector load: lane<32 handles even edges,
// lane>=32 odd edges, each lane loads uint2 (4 bf16) of its column group.
// Halves combined at the end via shfl_xor(32).
// ---------------------------------------------------------------------------
__global__ __launch_bounds__(256) void agg128_bf16_kernel(
    const unsigned short* __restrict__ h, const int* __restrict__ row_ptr,
    const int* __restrict__ csr, unsigned short* __restrict__ out) {
  int wid = (blockIdx.x * blockDim.x + threadIdx.x) >> 6;
  int lane = threadIdx.x & 63;
  if (wid >= N_NODES) return;
  int beg = __builtin_amdgcn_readfirstlane(row_ptr[wid]);
  int end = __builtin_amdgcn_readfirstlane(row_ptr[wid + 1]);
  int half = lane >> 5, l32 = lane & 31;
  float a0 = 0.f, a1 = 0.f, a2 = 0.f, a3 = 0.f;
  const unsigned short* hp = h + 4 * l32;
  int k = beg + half;
  for (; k + 2 < end; k += 4) {
    int s0 = csr[k];
    int s1 = csr[k + 2];
    uint2 v0 = *(const uint2*)(hp + (size_t)s0 * HID);
    uint2 v1 = *(const uint2*)(hp + (size_t)s1 * HID);
    a0 += bf2f(v0.x & 0xffff) + bf2f(v1.x & 0xffff);
    a1 += bf2f(v0.x >> 16) + bf2f(v1.x >> 16);
    a2 += bf2f(v0.y & 0xffff) + bf2f(v1.y & 0xffff);
    a3 += bf2f(v0.y >> 16) + bf2f(v1.y >> 16);
  }
  for (; k < end; k += 2) {
    int s = csr[k];
    uint2 v = *(const uint2*)(hp + (size_t)s * HID);
    a0 += bf2f(v.x & 0xffff);
    a1 += bf2f(v.x >> 16);
    a2 += bf2f(v.y & 0xffff);
    a3 += bf2f(v.y >> 16);
  }
  a0 += __shfl_xor(a0, 32, 64);
  a1 += __shfl_xor(a1, 32, 64);
  a2 += __shfl_xor(a2, 32, 64);
  a3 += __shfl_xor(a3, 32, 64);
  if (half == 0) {
    float inv = 1.0f / fmaxf((float)(end - beg), 1.0f);
    uint2 o;
    o.x = (unsigned)f2bf(a0 * inv) | ((unsigned)f2bf(a1 * inv) << 16);
    o.y = (unsigned)f2bf(a2 * inv) | ((unsigned)f2bf(a3 * inv) << 16);
    *(uint2*)(out + (size_t)wid * HID + 4 * l32) = o;
  }
}

// ---------------------------------------------------------------------------
// layer1 (K=8, f32 in, bf16 out)
// ---------------------------------------------------------------------------
__global__ __launch_bounds__(256) void layer1_kernel(const float* __restrict__ agg8,
                                                     const float* __restrict__ gx,
                                                     const float* __restrict__ Wl,
                                                     const float* __restrict__ Wr,
                                                     const float* __restrict__ b,
                                                     unsigned short* __restrict__ out) {
  __shared__ float wl[8][128];
  __shared__ float wr[8][128];
  for (int t = threadIdx.x; t < 1024; t += 256) {
    int j = t >> 3, k = t & 7;
    wl[k][j] = Wl[t];
    wr[k][j] = Wr[t];
  }
  __syncthreads();
  int t = blockIdx.x * blockDim.x + threadIdx.x;
  int i = t >> 7;
  int j = t & 127;
  if (i >= N_NODES) return;
  const float* a = agg8 + (size_t)i * 8;
  const float* g = gx + (size_t)i * 8;
  float acc = b[j];
#pragma unroll
  for (int k = 0; k < 8; ++k) acc += a[k] * wl[k][j] + g[k] * wr[k][j];
  out[(size_t)i * HID + j] = f2bf(fmaxf(acc, 0.0f));
}

// ---------------------------------------------------------------------------
// MFMA SAGE GEMM: bf16 in, f32 accum, bf16 out. BM=128, BN=128, BK=32.
// ---------------------------------------------------------------------------
__global__ __launch_bounds__(256) void sage_gemm_mfma_kernel(
    const unsigned short* __restrict__ A1, const unsigned short* __restrict__ A2,
    const unsigned short* __restrict__ Wb, const float* __restrict__ bias,
    unsigned short* __restrict__ C, int M, int do_relu) {
  __shared__ unsigned short Alds[128 * LDSP];
  __shared__ unsigned short Wlds[128 * LDSP];
  int tid = threadIdx.x;
  int wave = tid >> 6, lane = tid & 63;
  int l15 = lane & 15, g = lane >> 4;
  int row0 = blockIdx.x * 128;

  f32x4 acc[2][8];
#pragma unroll
  for (int m = 0; m < 2; ++m)
#pragma unroll
    for (int n = 0; n < 8; ++n) acc[m][n] = (f32x4){0.f, 0.f, 0.f, 0.f};

  for (int ks = 0; ks < 8; ++ks) {
    const unsigned short* Asrc = (ks < 4) ? A1 : A2;
    int k0 = (ks & 3) * 32;
#pragma unroll
    for (int it = 0; it < 2; ++it) {
      int c = tid + it * 256;
      int r = c >> 2, cc = c & 3;
      int gr = row0 + r;
      u16x8 v = {};
      if (gr < M) v = *(const u16x8*)(Asrc + (size_t)gr * HID + k0 + cc * 8);
      *(u16x8*)(&Alds[r * LDSP + cc * 8]) = v;
      u16x8 wv = *(const u16x8*)(Wb + r * 256 + ks * 32 + cc * 8);
      *(u16x8*)(&Wlds[r * LDSP + cc * 8]) = wv;
    }
    __syncthreads();

    bf16x8 a[2], w[8];
    int mrow = wave * 32;
#pragma unroll
    for (int m = 0; m < 2; ++m)
      a[m] = __builtin_bit_cast(bf16x8, *(const u16x8*)(&Alds[(mrow + 16 * m + l15) * LDSP + g * 8]));
#pragma unroll
    for (int n = 0; n < 8; ++n)
      w[n] = __builtin_bit_cast(bf16x8, *(const u16x8*)(&Wlds[(16 * n + l15) * LDSP + g * 8]));
#pragma unroll
    for (int m = 0; m < 2; ++m)
#pragma unroll
      for (int n = 0; n < 8; ++n)
        acc[m][n] = __builtin_amdgcn_mfma_f32_16x16x32_bf16(a[m], w[n], acc[m][n], 0, 0, 0);
    __syncthreads();
  }

#pragma unroll
  for (int n = 0; n < 8; ++n) {
    int col = 16 * n + l15;
    float bv = bias[col];
#pragma unroll
    for (int m = 0; m < 2; ++m) {
#pragma unroll
      for (int r = 0; r < 4; ++r) {
        int grow = row0 + wave * 32 + 16 * m + g * 4 + r;
        if (grow < M) {
          float v = acc[m][n][r] + bv;
          if (do_relu) v = fmaxf(v, 0.0f);
          C[(size_t)grow * HID + col] = f2bf(v);
        }
      }
    }
  }
}

// ---------------------------------------------------------------------------
// layer4 projections (h bf16) + scalar aggregation
// ---------------------------------------------------------------------------
__global__ __launch_bounds__(256) void zzr_bf16_kernel(const unsigned short* __restrict__ h,
                                                       const float* __restrict__ Wl4,
                                                       const float* __restrict__ Wr4,
                                                       float* __restrict__ z,
                                                       float* __restrict__ zr) {
  int wid = (blockIdx.x * blockDim.x + threadIdx.x) >> 6;
  int lane = threadIdx.x & 63;
  if (wid >= N_NODES) return;
  unsigned v = *(const unsigned*)(h + (size_t)wid * HID + 2 * lane);
  float vx = bf2f(v & 0xffff), vy = bf2f(v >> 16);
  float2 wl = *(const float2*)(Wl4 + 2 * lane);
  float2 wr = *(const float2*)(Wr4 + 2 * lane);
  float a = vx * wl.x + vy * wl.y;
  float b = vx * wr.x + vy * wr.y;
#pragma unroll
  for (int off = 32; off > 0; off >>= 1) {
    a += __shfl_xor(a, off, 64);
    b += __shfl_xor(b, off, 64);
  }
  if (lane == 0) {
    z[wid] = a;
    zr[wid] = b;
  }
}

__global__ void gout_kernel(const float* __restrict__ z, const float* __restrict__ zr,
                            const int* __restrict__ row_ptr, const int* __restrict__ csr,
                            const float* __restrict__ bs4, float* __restrict__ gout) {
  int i = blockIdx.x * blockDim.x + threadIdx.x;
  if (i >= N_NODES) return;
  int beg = row_ptr[i], end = row_ptr[i + 1];
  float s = 0.0f;
  int k = beg;
  for (; k + 2 <= end; k += 2) s += z[csr[k]] + z[csr[k + 1]];
  for (; k < end; ++k) s += z[csr[k]];
  float d = fmaxf((float)(end - beg), 1.0f);
  gout[i] = s / d + zr[i] + bs4[0];
}

// ---------------------------------------------------------------------------
extern "C" void kernel_launch(void* const* d_in, const int* in_sizes, int n_in,
                              void* d_out, int out_size, void* d_ws, size_t ws_size,
                              hipStream_t stream) {
  const float* xdata = (const float*)d_in[0];
  const float* x = (const float*)d_in[1];
  const float* pos = (const float*)d_in[2];
  const int* ei = (const int*)d_in[3];
  const int* batch = (const int*)d_in[4];
  const float* w1 = (const float*)d_in[5];
  const float* b1 = (const float*)d_in[6];
  const float* w2 = (const float*)d_in[7];
  const float* b2 = (const float*)d_in[8];
  const float* w3 = (const float*)d_in[9];
  const float* b3 = (const float*)d_in[10];
  const float* Wl1 = (const float*)d_in[11];
  const float* Wr1 = (const float*)d_in[12];
  const float* bs1 = (const float*)d_in[13];
  const float* Wl2 = (const float*)d_in[14];
  const float* Wr2 = (const float*)d_in[15];
  const float* bs2 = (const float*)d_in[16];
  const float* Wl3 = (const float*)d_in[17];
  const float* Wr3 = (const float*)d_in[18];
  const float* bs3 = (const float*)d_in[19];
  const float* Wl4 = (const float*)d_in[20];
  const float* Wr4 = (const float*)d_in[21];
  const float* bs4 = (const float*)d_in[22];

  float* x1_out = (float*)d_out;
  float* gout = (float*)d_out + (size_t)NBATCH * IMG;

  char* ws = (char*)d_ws;
  size_t off = 0;
  auto take = [&](size_t bytes) -> char* {
    char* p = ws + off;
    off = (off + bytes + 255) & ~(size_t)255;
    return p;
  };
  float* hbuf1 = (float*)take((size_t)NBATCH * 16 * IMG * 4);  // conv h1 NHWC bf16 / sage h1,h3
  float* hbuf2 = (float*)take((size_t)NBATCH * 16 * IMG * 4);  // conv h2 NHWC bf16 / sage h2
  unsigned short* aggb = (unsigned short*)take((size_t)N_NODES * HID * 2);
  float* agg8o = (float*)take((size_t)N_NODES * 8 * 4);
  float* gx = (float*)take((size_t)N_NODES * 8 * 4);
  int* row_ptr = (int*)take((size_t)(N_NODES + 1) * 4);
  int* csr = (int*)take((size_t)N_EDGES * 4);
  int* cnt_mat = (int*)take((size_t)NBKT * NB * 4);
  int* rowscan = (int*)take((size_t)NBKT * NB * 4);
  int* row_total = (int*)take((size_t)NBKT * 4);
  int* bucket_base = (int*)take((size_t)NBKT * 4);
  int* bucket_data = (int*)take((size_t)N_EDGES * 4);
  float* z = (float*)take((size_t)N_NODES * 4);
  float* zr = (float*)take((size_t)N_NODES * 4);
  unsigned short* Wb2 = (unsigned short*)take((size_t)128 * 256 * 2);
  unsigned short* Wb3 = (unsigned short*)take((size_t)128 * 256 * 2);
  unsigned short* Wc1 = (unsigned short*)take((size_t)12 * 128 * 2);
  unsigned short* Wc2 = (unsigned short*)take((size_t)20 * 128 * 2);
  (void)ws_size;

  unsigned short* h1c = (unsigned short*)hbuf1;
  unsigned short* h2c = (unsigned short*)hbuf2;
  unsigned short* h1 = (unsigned short*)hbuf1;
  unsigned short* h2 = (unsigned short*)hbuf2;
  unsigned short* h3 = (unsigned short*)hbuf1;

  const int nblk_n = (N_NODES + 255) / 256;
  const int nblk_conv = NBATCH * 16;            // 512
  const int nblk_gemm = (N_NODES + 127) / 128;  // 391

  // ---- weight packs (one launch) ----
  hipLaunchKernelGGL(pack_all_kernel, dim3(273), dim3(256), 0, stream, Wl2, Wr2, Wl3, Wr3, w1,
                     w2, Wb2, Wb3, Wc1, Wc2);

  // ---- CNN stack (MFMA, NHWC bf16 intermediates) ----
  hipLaunchKernelGGL(conv1_mfma_kernel, dim3(nblk_conv), dim3(256), 0, stream, xdata, Wc1, b1,
                     h1c);
  hipLaunchKernelGGL(conv2_mfma_kernel, dim3(nblk_conv), dim3(256), 0, stream, h1c, Wc2, b2,
                     h2c);
  hipLaunchKernelGGL(conv3_f32_kernel, dim3(NBATCH * IMG / 256), dim3(256), 0, stream, h2c, w3,
                     b3, x1_out);

  // ---- CSR build (atomic-free counting sort) ----
  hipLaunchKernelGGL(count_kernel, dim3(NB), dim3(256), 0, stream, ei, cnt_mat);
  hipLaunchKernelGGL(scan_rows_kernel, dim3(NBKT), dim3(1024), 0, stream, cnt_mat, rowscan,
                     row_total);
  hipLaunchKernelGGL(scan_roots_kernel, dim3(1), dim3(256), 0, stream, row_total, bucket_base,
                     row_ptr);
  hipLaunchKernelGGL(scatter2_kernel, dim3(NB), dim3(256), 0, stream, ei, rowscan, bucket_base,
                     bucket_data);
  hipLaunchKernelGGL(bucketB_kernel, dim3(NBKT), dim3(256), 0, stream, row_total, bucket_base,
                     bucket_data, row_ptr, csr);

  // ---- node features ----
  hipLaunchKernelGGL(gather_gx_kernel, dim3(nblk_n), dim3(256), 0, stream, x, pos, batch,
                     x1_out, gx);

  // ---- layer 1 (K=8) -> h1 bf16 ----
  hipLaunchKernelGGL(agg8_kernel, dim3((N_NODES * 8 + 255) / 256), dim3(256), 0, stream, gx,
                     row_ptr, csr, agg8o);
  hipLaunchKernelGGL(layer1_kernel, dim3((N_NODES * 128) / 256), dim3(256), 0, stream, agg8o,
                     gx, Wl1, Wr1, bs1, h1);

  // ---- layer 2 ----
  hipLaunchKernelGGL(agg128_bf16_kernel, dim3(N_NODES / 4), dim3(256), 0, stream, h1, row_ptr,
                     csr, aggb);
  hipLaunchKernelGGL(sage_gemm_mfma_kernel, dim3(nblk_gemm), dim3(256), 0, stream, aggb, h1,
                     Wb2, bs2, h2, N_NODES, 1);

  // ---- layer 3 ----
  hipLaunchKernelGGL(agg128_bf16_kernel, dim3(N_NODES / 4), dim3(256), 0, stream, h2, row_ptr,
                     csr, aggb);
  hipLaunchKernelGGL(sage_gemm_mfma_kernel, dim3(nblk_gemm), dim3(256), 0, stream, aggb, h2,
                     Wb3, bs3, h3, N_NODES, 1);

  // ---- layer 4 ----
  hipLaunchKernelGGL(zzr_bf16_kernel, dim3(N_NODES / 4), dim3(256), 0, stream, h3, Wl4, Wr4, z,
                     zr);
  hipLaunchKernelGGL(gout_kernel, dim3(nblk_n), dim3(256), 0, stream, z, zr, row_ptr, csr, bs4,
                     gout);
}

// Round 9
// 199.444 us; speedup vs baseline: 1.1994x; 1.1994x over previous
//
#include <hip/hip_runtime.h>

#define N_NODES 50000
#define N_EDGES 800000
#define NBATCH 32
#define HWDIM 128
#define IMG (HWDIM * HWDIM)
#define HID 128
#define NBKT ((N_NODES + 255) / 256)  // 196 buckets of 256 dst nodes
#define NB 625                        // partition blocks
#define EPB 1280                      // edges per partition block
#define LDSP 40  // sage gemm LDS row stride (bf16)

typedef float f32x4 __attribute__((ext_vector_type(4)));
typedef __bf16 bf16x8 __attribute__((ext_vector_type(8)));
typedef unsigned short u16x8 __attribute__((ext_vector_type(8)));

__device__ __forceinline__ unsigned short f2bf(float x) {
  unsigned u = __builtin_bit_cast(unsigned, x);
  u = (u + 0x7FFF + ((u >> 16) & 1)) >> 16;
  return (unsigned short)u;
}
__device__ __forceinline__ float bf2f(unsigned short h) {
  return __builtin_bit_cast(float, (unsigned)h << 16);
}

// ---------------------------------------------------------------------------
// Merged weight-pack kernel (Wb2, Wb3, Wc1, Wc2)
// ---------------------------------------------------------------------------
__global__ void pack_all_kernel(const float* __restrict__ Wl2, const float* __restrict__ Wr2,
                                const float* __restrict__ Wl3, const float* __restrict__ Wr3,
                                const float* __restrict__ w1, const float* __restrict__ w2,
                                unsigned short* __restrict__ Wb2, unsigned short* __restrict__ Wb3,
                                unsigned short* __restrict__ Wc1, unsigned short* __restrict__ Wc2) {
  int t = blockIdx.x * blockDim.x + threadIdx.x;
  if (t < 65536) {
    const float* Wl = (t < 32768) ? Wl2 : Wl3;
    const float* Wr = (t < 32768) ? Wr2 : Wr3;
    unsigned short* Wb = (t < 32768) ? Wb2 : Wb3;
    int tt = t & 32767;
    int j = tt >> 8, k = tt & 255;
    float v = (k < 128) ? Wl[j * 128 + k] : Wr[j * 128 + (k - 128)];
    Wb[tt] = f2bf(v);
    return;
  }
  int t2 = t - 65536;
  const float* w;
  unsigned short* dst;
  int CIN, idx;
  if (t2 < 1536) {
    w = w1; dst = Wc1; CIN = 8; idx = t2;
  } else if (t2 < 1536 + 2560) {
    w = w2; dst = Wc2; CIN = 16; idx = t2 - 1536;
  } else {
    return;
  }
  int j = idx & 7;
  int n = (idx >> 3) & 15;
  int sgi = idx >> 7;
  int k = sgi * 8 + j;
  int tap = k / CIN;
  int ci = k % CIN;
  dst[idx] = (tap < 9) ? f2bf(w[(n * CIN + ci) * 9 + tap]) : (unsigned short)0;
}

// ---------------------------------------------------------------------------
// MFMA conv1: CIN=8 (f32 NCHW input), COUT=16, relu, out NHWC bf16.
// ---------------------------------------------------------------------------
__global__ __launch_bounds__(256) void conv1_mfma_kernel(
    const float* __restrict__ in, const unsigned short* __restrict__ Wc,
    const float* __restrict__ bias, unsigned short* __restrict__ out) {
  __shared__ unsigned short lds[10 * 130 * 8];
  int tid = threadIdx.x;
  int img = blockIdx.x >> 4;
  int y0 = (blockIdx.x & 15) * 8;
  int lane = tid & 63, wave = tid >> 6;
  int l15 = lane & 15, g = lane >> 4;

  const float* sb = in + (size_t)img * 8 * IMG;
#pragma unroll
  for (int i = 0; i < 5; ++i) {
    int idx = tid + i * 256;
    int r = idx >> 7;
    int x = idx & 127;
    int gy = y0 - 1 + r;
    u16x8 v = {};
    if ((unsigned)gy < (unsigned)HWDIM) {
      const float* sp = sb + gy * HWDIM + x;
#pragma unroll
      for (int ci = 0; ci < 8; ++ci) v[ci] = f2bf(sp[ci * IMG]);
    }
    *(u16x8*)&lds[(r * 130 + x + 1) * 8] = v;
  }
  if (tid < 20) {
    int r = tid >> 1, c = (tid & 1) * 129;
    *(u16x8*)&lds[(r * 130 + c) * 8] = (u16x8){};
  }

  bf16x8 bfrag[3];
  int adel[3];
#pragma unroll
  for (int s = 0; s < 3; ++s) {
    bfrag[s] = __builtin_bit_cast(bf16x8, *(const u16x8*)(Wc + (((s * 4 + g) * 16) + l15) * 8));
    int tap = (32 * s + 8 * g) / 8;
    tap = tap > 8 ? 8 : tap;
    adel[s] = ((tap / 3) * 130 + (tap % 3)) * 8;
  }
  float bv = bias[l15];
  __syncthreads();

#pragma unroll
  for (int ti = 0; ti < 16; ++ti) {
    int tile = wave * 16 + ti;
    int ly = tile >> 3, xb = (tile & 7) * 16;
    int tb = (ly * 130 + xb + l15) * 8;
    f32x4 acc = {};
#pragma unroll
    for (int s = 0; s < 3; ++s) {
      bf16x8 a = __builtin_bit_cast(bf16x8, *(const u16x8*)&lds[tb + adel[s]]);
      acc = __builtin_amdgcn_mfma_f32_16x16x32_bf16(a, bfrag[s], acc, 0, 0, 0);
    }
    size_t base = (((size_t)img * HWDIM + y0 + ly) * HWDIM + xb);
#pragma unroll
    for (int r = 0; r < 4; ++r) {
      float v = fmaxf(acc[r] + bv, 0.0f);
      out[(base + g * 4 + r) * 16 + l15] = f2bf(v);
    }
  }
}

// ---------------------------------------------------------------------------
// MFMA conv2: CIN=16 (NHWC bf16 input), COUT=16, relu, out NHWC bf16.
// ---------------------------------------------------------------------------
__global__ __launch_bounds__(256) void conv2_mfma_kernel(
    const unsigned short* __restrict__ in, const unsigned short* __restrict__ Wc,
    const float* __restrict__ bias, unsigned short* __restrict__ out) {
  __shared__ unsigned short lds[10 * 130 * 24];
  int tid = threadIdx.x;
  int img = blockIdx.x >> 4;
  int y0 = (blockIdx.x & 15) * 8;
  int lane = tid & 63, wave = tid >> 6;
  int l15 = lane & 15, g = lane >> 4;

  const unsigned short* sb = in + (size_t)img * IMG * 16;
#pragma unroll
  for (int i = 0; i < 10; ++i) {
    int idx = tid + i * 256;
    int r = idx >> 8;
    int x = (idx & 255) >> 1;
    int hh = idx & 1;
    int gy = y0 - 1 + r;
    u16x8 v = {};
    if ((unsigned)gy < (unsigned)HWDIM) v = *(const u16x8*)(sb + ((size_t)gy * HWDIM + x) * 16 + hh * 8);
    *(u16x8*)&lds[(r * 130 + x + 1) * 24 + hh * 8] = v;
  }
  if (tid < 20) {
    int r = tid >> 1, c = (tid & 1) * 129;
#pragma unroll
    for (int q = 0; q < 3; ++q) *(u16x8*)&lds[(r * 130 + c) * 24 + q * 8] = (u16x8){};
  }

  bf16x8 bfrag[5];
  int adel[5];
#pragma unroll
  for (int s = 0; s < 5; ++s) {
    bfrag[s] = __builtin_bit_cast(bf16x8, *(const u16x8*)(Wc + (((s * 4 + g) * 16) + l15) * 8));
    int tap = (32 * s + 8 * g) / 16;
    tap = tap > 8 ? 8 : tap;
    adel[s] = ((tap / 3) * 130 + (tap % 3)) * 24 + (g & 1) * 8;
  }
  float bv = bias[l15];
  __syncthreads();

#pragma unroll
  for (int ti = 0; ti < 16; ++ti) {
    int tile = wave * 16 + ti;
    int ly = tile >> 3, xb = (tile & 7) * 16;
    int tb = (ly * 130 + xb + l15) * 24;
    f32x4 acc = {};
#pragma unroll
    for (int s = 0; s < 5; ++s) {
      bf16x8 a = __builtin_bit_cast(bf16x8, *(const u16x8*)&lds[tb + adel[s]]);
      acc = __builtin_amdgcn_mfma_f32_16x16x32_bf16(a, bfrag[s], acc, 0, 0, 0);
    }
    size_t base = (((size_t)img * HWDIM + y0 + ly) * HWDIM + xb);
#pragma unroll
    for (int r = 0; r < 4; ++r) {
      float v = fmaxf(acc[r] + bv, 0.0f);
      out[(base + g * 4 + r) * 16 + l15] = f2bf(v);
    }
  }
}

// ---------------------------------------------------------------------------
// conv3: CIN=16 (NHWC bf16), COUT=1, no relu, f32 NCHW out. 1 px/thread.
// ---------------------------------------------------------------------------
__global__ __launch_bounds__(256) void conv3_f32_kernel(const unsigned short* __restrict__ h2,
                                                        const float* __restrict__ w3,
                                                        const float* __restrict__ b3,
                                                        float* __restrict__ x1) {
  __shared__ float w9[9][16];
  __shared__ float b3s;
  int tid = threadIdx.x;
  if (tid < 144) {
    int ci = tid & 15, tap = tid >> 4;
    w9[tap][ci] = w3[ci * 9 + tap];
  }
  if (tid == 144) b3s = b3[0];
  __syncthreads();
  int t = blockIdx.x * 256 + tid;
  int x = t & 127;
  int y = (t >> 7) & 127;
  int img = t >> 14;
  float acc = b3s;
#pragma unroll
  for (int dy = 0; dy < 3; ++dy) {
    int yy = y + dy - 1;
    if ((unsigned)yy >= (unsigned)HWDIM) continue;
#pragma unroll
    for (int dx = 0; dx < 3; ++dx) {
      int xx = x + dx - 1;
      if ((unsigned)xx >= (unsigned)HWDIM) continue;
      const u16x8* p = (const u16x8*)(h2 + (((size_t)img * HWDIM + yy) * HWDIM + xx) * 16);
      u16x8 lo = p[0], hi = p[1];
      const float* wt = w9[dy * 3 + dx];
#pragma unroll
      for (int j = 0; j < 8; ++j) acc += bf2f(lo[j]) * wt[j];
#pragma unroll
      for (int j = 0; j < 8; ++j) acc += bf2f(hi[j]) * wt[8 + j];
    }
  }
  x1[(size_t)img * IMG + y * HWDIM + x] = acc;
}

// ---------------------------------------------------------------------------
// Atomic-free bucketed CSR build (counting sort by 256-node buckets).
// ---------------------------------------------------------------------------
__global__ __launch_bounds__(256) void count_kernel(const int* __restrict__ ei,
                                                    int* __restrict__ cnt_mat) {
  __shared__ int hist[NBKT];
  int t = threadIdx.x;
  if (t < NBKT) hist[t] = 0;
  __syncthreads();
  int e0 = blockIdx.x * EPB;
#pragma unroll
  for (int i = 0; i < EPB / 256; ++i) {
    int d = ei[N_EDGES + e0 + i * 256 + t];
    atomicAdd(&hist[d >> 8], 1);
  }
  __syncthreads();
  if (t < NBKT) cnt_mat[t * NB + blockIdx.x] = hist[t];
}

__global__ __launch_bounds__(1024) void scan_rows_kernel(const int* __restrict__ cnt_mat,
                                                         int* __restrict__ rowscan,
                                                         int* __restrict__ row_total) {
  __shared__ int wsum[16];
  int row = blockIdx.x;
  int t = threadIdx.x;
  int lane = t & 63, w = t >> 6;
  int v = (t < NB) ? cnt_mat[row * NB + t] : 0;
  int s = v;
#pragma unroll
  for (int off = 1; off < 64; off <<= 1) {
    int u = __shfl_up(s, off, 64);
    if (lane >= off) s += u;
  }
  if (lane == 63) wsum[w] = s;
  __syncthreads();
  if (w == 0 && lane < 16) {
    int ws = wsum[lane];
#pragma unroll
    for (int off = 1; off < 16; off <<= 1) {
      int u = __shfl_up(ws, off, 64);
      if (lane >= off) ws += u;
    }
    wsum[lane] = ws;
  }
  __syncthreads();
  int base = (w > 0) ? wsum[w - 1] : 0;
  int incl = s + base;
  if (t < NB) rowscan[row * NB + t] = incl - v;
  if (t == NB - 1) row_total[row] = incl;
}

// helper: block-wide exclusive scan of row_total[0..NBKT) into bb[] (256 thr)
__device__ __forceinline__ void scan_bases(const int* __restrict__ row_total, int* bb,
                                           int* wsum) {
  int t = threadIdx.x;
  int lane = t & 63, w = t >> 6;
  int v = (t < NBKT) ? row_total[t] : 0;
  int s = v;
#pragma unroll
  for (int off = 1; off < 64; off <<= 1) {
    int u = __shfl_up(s, off, 64);
    if (lane >= off) s += u;
  }
  if (lane == 63) wsum[w] = s;
  __syncthreads();
  int add = 0;
#pragma unroll
  for (int i = 0; i < 4; ++i)
    if (i < w) add += wsum[i];
  if (t < NBKT) bb[t] = s + add - v;
  __syncthreads();
}

__global__ __launch_bounds__(256) void scatter2_kernel(const int* __restrict__ ei,
                                                       const int* __restrict__ rowscan,
                                                       const int* __restrict__ row_total,
                                                       int* __restrict__ bucket_data) {
  __shared__ int bb[NBKT];
  __shared__ int lhist[NBKT];
  __shared__ int lexcl[NBKT];
  __shared__ int gb[NBKT];
  __shared__ int wsum[4];
  __shared__ int lds_pack[EPB];
  __shared__ int lds_dest[EPB];
  int t = threadIdx.x;
  int blk = blockIdx.x;
  scan_bases(row_total, bb, wsum);
  if (t < NBKT) lhist[t] = 0;
  __syncthreads();
  int e0 = blk * EPB;
  int myb[EPB / 256], myp[EPB / 256], mypack[EPB / 256];
#pragma unroll
  for (int i = 0; i < EPB / 256; ++i) {
    int e = e0 + i * 256 + t;
    int s = ei[e];
    int d = ei[N_EDGES + e];
    int b = d >> 8;
    myb[i] = b;
    mypack[i] = s | ((d & 255) << 16);
    myp[i] = atomicAdd(&lhist[b], 1);
  }
  __syncthreads();
  {
    int lane = t & 63, w = t >> 6;
    int v = (t < NBKT) ? lhist[t] : 0;
    int s = v;
#pragma unroll
    for (int off = 1; off < 64; off <<= 1) {
      int u = __shfl_up(s, off, 64);
      if (lane >= off) s += u;
    }
    if (lane == 63) wsum[w] = s;
    __syncthreads();
    int add = 0;
#pragma unroll
    for (int i = 0; i < 4; ++i)
      if (i < w) add += wsum[i];
    if (t < NBKT) {
      lexcl[t] = s + add - v;
      gb[t] = bb[t] + rowscan[t * NB + blk];
    }
  }
  __syncthreads();
#pragma unroll
  for (int i = 0; i < EPB / 256; ++i) {
    int slot = lexcl[myb[i]] + myp[i];
    lds_pack[slot] = mypack[i];
    lds_dest[slot] = gb[myb[i]] + myp[i];
  }
  __syncthreads();
#pragma unroll
  for (int i = 0; i < EPB / 256; ++i) {
    int slot = i * 256 + t;
    bucket_data[lds_dest[slot]] = lds_pack[slot];
  }
}

__global__ __launch_bounds__(256) void bucketB_kernel(const int* __restrict__ row_total,
                                                      const int* __restrict__ bucket_data,
                                                      int* __restrict__ row_ptr,
                                                      int* __restrict__ csr) {
  __shared__ int bb[NBKT];
  __shared__ int cnts[256];
  __shared__ int curs[256];
  __shared__ int wsum[4];
  int b = blockIdx.x;
  int t = threadIdx.x;
  scan_bases(row_total, bb, wsum);
  int cnt = row_total[b];
  int base = bb[b];
  if (b == 0 && t == 0) row_ptr[N_NODES] = N_EDGES;
  cnts[t] = 0;
  __syncthreads();
  const int* bd = bucket_data + base;
  for (int k = t; k < cnt; k += 256) {
    int v = bd[k];
    atomicAdd(&cnts[(v >> 16) & 255], 1);
  }
  __syncthreads();
  int v = cnts[t];
  int lane = t & 63, w = t >> 6;
  int s = v;
#pragma unroll
  for (int off = 1; off < 64; off <<= 1) {
    int u = __shfl_up(s, off, 64);
    if (lane >= off) s += u;
  }
  if (lane == 63) wsum[w] = s;
  __syncthreads();
  int add = 0;
#pragma unroll
  for (int i = 0; i < 4; ++i)
    if (i < w) add += wsum[i];
  int excl = s + add - v;
  int node = b * 256 + t;
  if (node < N_NODES) row_ptr[node] = base + excl;
  curs[t] = excl;
  __syncthreads();
  for (int k = t; k < cnt; k += 256) {
    int vv = bd[k];
    int p = atomicAdd(&curs[(vv >> 16) & 255], 1);
    csr[base + p] = vv & 0xffff;
  }
}

// ---------------------------------------------------------------------------
// gather node features: gx = [x0, x1, x5, x6, x7, pos0, pos1, cnng]
// ---------------------------------------------------------------------------
__global__ void gather_gx_kernel(const float* __restrict__ x, const float* __restrict__ pos,
                                 const int* __restrict__ batch, const float* __restrict__ x1,
                                 float* __restrict__ gx) {
  int t = blockIdx.x * blockDim.x + threadIdx.x;
  if (t >= N_NODES) return;
  float px = pos[2 * t + 0];
  float py = pos[2 * t + 1];
  float fx = px / 20.0f * 127.0f;
  float fy = py / 20.0f * 127.0f;
  int cx = (int)rintf(fx);
  int cy = (int)rintf(fy);
  cx = min(max(cx, 0), HWDIM - 1);
  cy = min(max(cy, 0), HWDIM - 1);
  int b = batch[t];
  float cn = x1[(size_t)b * IMG + cy * HWDIM + cx];
  const float* xr = x + (size_t)t * 8;
  float* g = gx + (size_t)t * 8;
  g[0] = xr[0];
  g[1] = xr[1];
  g[2] = xr[5];
  g[3] = xr[6];
  g[4] = xr[7];
  g[5] = px;
  g[6] = py;
  g[7] = cn;
}

// ---------------------------------------------------------------------------
// Fused layer 1: agg8 (CSR mean of gx) + [agg,gx] @ [Wl1;Wr1] + bias, relu.
// Block = 256 thr = 32 nodes (8 lanes/node) for agg; then 8 thr/node x 16 cols.
// ---------------------------------------------------------------------------
__global__ __launch_bounds__(256) void l1_fused_kernel(
    const float* __restrict__ gx, const int* __restrict__ row_ptr,
    const int* __restrict__ csr, const float* __restrict__ Wl,
    const float* __restrict__ Wr, const float* __restrict__ b,
    unsigned short* __restrict__ out) {
  __shared__ float wl[8][128];
  __shared__ float wr[8][128];
  __shared__ float aggs[32][8];
  int tid = threadIdx.x;
  for (int t = tid; t < 1024; t += 256) {
    int j = t >> 3, k = t & 7;
    wl[k][j] = Wl[t];
    wr[k][j] = Wr[t];
  }
  int node0 = blockIdx.x * 32;
  {
    int i = node0 + (tid >> 3);
    int f = tid & 7;
    float acc = 0.0f;
    if (i < N_NODES) {
      int beg = row_ptr[i], end = row_ptr[i + 1];
      int k = beg;
      for (; k + 2 <= end; k += 2) {
        int s0 = csr[k], s1 = csr[k + 1];
        acc += gx[(size_t)s0 * 8 + f] + gx[(size_t)s1 * 8 + f];
      }
      for (; k < end; ++k) acc += gx[(size_t)csr[k] * 8 + f];
      acc /= fmaxf((float)(end - beg), 1.0f);
    }
    aggs[tid >> 3][f] = acc;
  }
  __syncthreads();
  int nl = tid >> 3;
  int i = node0 + nl;
  if (i >= N_NODES) return;
  float av[8], gv[8];
#pragma unroll
  for (int k = 0; k < 8; ++k) {
    av[k] = aggs[nl][k];
    gv[k] = gx[(size_t)i * 8 + k];
  }
  int c0 = (tid & 7) * 16;
#pragma unroll
  for (int c = 0; c < 16; ++c) {
    int col = c0 + c;
    float acc = b[col];
#pragma unroll
    for (int k = 0; k < 8; ++k) acc += av[k] * wl[k][col] + gv[k] * wr[k][col];
    out[(size_t)i * HID + col] = f2bf(fmaxf(acc, 0.0f));
  }
}

// ---------------------------------------------------------------------------
// CSR aggregation, C=128, bf16 in/out, f32 accum. One wave/node (R7 form).
// ---------------------------------------------------------------------------
__global__ __launch_bounds__(256) void agg128_bf16_kernel(
    const unsigned short* __restrict__ h, const int* __restrict__ row_ptr,
    const int* __restrict__ csr, unsigned short* __restrict__ out) {
  int wid = (blockIdx.x * blockDim.x + threadIdx.x) >> 6;
  int lane = threadIdx.x & 63;
  if (wid >= N_NODES) return;
  int beg = __builtin_amdgcn_readfirstlane(row_ptr[wid]);
  int end = __builtin_amdgcn_readfirstlane(row_ptr[wid + 1]);
  float ax = 0.0f, ay = 0.0f;
  const unsigned short* hp = h + 2 * lane;
  int k = beg;
  for (; k + 4 <= end; k += 4) {
    int s0 = csr[k];
    int s1 = csr[k + 1];
    int s2 = csr[k + 2];
    int s3 = csr[k + 3];
    unsigned v0 = *(const unsigned*)(hp + (size_t)s0 * HID);
    unsigned v1 = *(const unsigned*)(hp + (size_t)s1 * HID);
    unsigned v2 = *(const unsigned*)(hp + (size_t)s2 * HID);
    unsigned v3 = *(const unsigned*)(hp + (size_t)s3 * HID);
    ax += (bf2f(v0 & 0xffff) + bf2f(v1 & 0xffff)) + (bf2f(v2 & 0xffff) + bf2f(v3 & 0xffff));
    ay += (bf2f(v0 >> 16) + bf2f(v1 >> 16)) + (bf2f(v2 >> 16) + bf2f(v3 >> 16));
  }
  for (; k < end; ++k) {
    int s = csr[k];
    unsigned v = *(const unsigned*)(hp + (size_t)s * HID);
    ax += bf2f(v & 0xffff);
    ay += bf2f(v >> 16);
  }
  float inv = 1.0f / fmaxf((float)(end - beg), 1.0f);
  unsigned o = (unsigned)f2bf(ax * inv) | ((unsigned)f2bf(ay * inv) << 16);
  *(unsigned*)(out + (size_t)wid * HID + 2 * lane) = o;
}

// ---------------------------------------------------------------------------
// MFMA SAGE GEMM: bf16 in, f32 accum, bf16 out. BM=64, BN=128, BK=32.
// Grid = ceil(M/64) = 782 blocks -> ~3 blocks/CU. Wave = 16 rows x 128 cols.
// ---------------------------------------------------------------------------
__global__ __launch_bounds__(256) void sage_gemm_mfma_kernel(
    const unsigned short* __restrict__ A1, const unsigned short* __restrict__ A2,
    const unsigned short* __restrict__ Wb, const float* __restrict__ bias,
    unsigned short* __restrict__ C, int M, int do_relu) {
  __shared__ unsigned short Alds[64 * LDSP];
  __shared__ unsigned short Wlds[128 * LDSP];
  int tid = threadIdx.x;
  int wave = tid >> 6, lane = tid & 63;
  int l15 = lane & 15, g = lane >> 4;
  int row0 = blockIdx.x * 64;

  f32x4 acc[8];
#pragma unroll
  for (int n = 0; n < 8; ++n) acc[n] = (f32x4){0.f, 0.f, 0.f, 0.f};

  for (int ks = 0; ks < 8; ++ks) {
    const unsigned short* Asrc = (ks < 4) ? A1 : A2;
    int k0 = (ks & 3) * 32;
    {
      int r = tid >> 2, cc = tid & 3;  // 64 rows x 4 chunks
      int gr = row0 + r;
      u16x8 v = {};
      if (gr < M) v = *(const u16x8*)(Asrc + (size_t)gr * HID + k0 + cc * 8);
      *(u16x8*)(&Alds[r * LDSP + cc * 8]) = v;
    }
#pragma unroll
    for (int it = 0; it < 2; ++it) {
      int c = tid + it * 256;
      int j = c >> 2, cc = c & 3;
      u16x8 wv = *(const u16x8*)(Wb + j * 256 + ks * 32 + cc * 8);
      *(u16x8*)(&Wlds[j * LDSP + cc * 8]) = wv;
    }
    __syncthreads();

    bf16x8 a = __builtin_bit_cast(bf16x8, *(const u16x8*)(&Alds[(wave * 16 + l15) * LDSP + g * 8]));
#pragma unroll
    for (int n = 0; n < 8; ++n) {
      bf16x8 w = __builtin_bit_cast(bf16x8, *(const u16x8*)(&Wlds[(16 * n + l15) * LDSP + g * 8]));
      acc[n] = __builtin_amdgcn_mfma_f32_16x16x32_bf16(a, w, acc[n], 0, 0, 0);
    }
    __syncthreads();
  }

#pragma unroll
  for (int n = 0; n < 8; ++n) {
    int col = 16 * n + l15;
    float bv = bias[col];
#pragma unroll
    for (int r = 0; r < 4; ++r) {
      int grow = row0 + wave * 16 + g * 4 + r;
      if (grow < M) {
        float v = acc[n][r] + bv;
        if (do_relu) v = fmaxf(v, 0.0f);
        C[(size_t)grow * HID + col] = f2bf(v);
      }
    }
  }
}

// ---------------------------------------------------------------------------
// layer4 projections (h bf16) + scalar aggregation
// ---------------------------------------------------------------------------
__global__ __launch_bounds__(256) void zzr_bf16_kernel(const unsigned short* __restrict__ h,
                                                       const float* __restrict__ Wl4,
                                                       const float* __restrict__ Wr4,
                                                       float* __restrict__ z,
                                                       float* __restrict__ zr) {
  int wid = (blockIdx.x * blockDim.x + threadIdx.x) >> 6;
  int lane = threadIdx.x & 63;
  if (wid >= N_NODES) return;
  unsigned v = *(const unsigned*)(h + (size_t)wid * HID + 2 * lane);
  float vx = bf2f(v & 0xffff), vy = bf2f(v >> 16);
  float2 wl = *(const float2*)(Wl4 + 2 * lane);
  float2 wr = *(const float2*)(Wr4 + 2 * lane);
  float a = vx * wl.x + vy * wl.y;
  float b = vx * wr.x + vy * wr.y;
#pragma unroll
  for (int off = 32; off > 0; off >>= 1) {
    a += __shfl_xor(a, off, 64);
    b += __shfl_xor(b, off, 64);
  }
  if (lane == 0) {
    z[wid] = a;
    zr[wid] = b;
  }
}

__global__ void gout_kernel(const float* __restrict__ z, const float* __restrict__ zr,
                            const int* __restrict__ row_ptr, const int* __restrict__ csr,
                            const float* __restrict__ bs4, float* __restrict__ gout) {
  int i = blockIdx.x * blockDim.x + threadIdx.x;
  if (i >= N_NODES) return;
  int beg = row_ptr[i], end = row_ptr[i + 1];
  float s = 0.0f;
  int k = beg;
  for (; k + 2 <= end; k += 2) s += z[csr[k]] + z[csr[k + 1]];
  for (; k < end; ++k) s += z[csr[k]];
  float d = fmaxf((float)(end - beg), 1.0f);
  gout[i] = s / d + zr[i] + bs4[0];
}

// ---------------------------------------------------------------------------
extern "C" void kernel_launch(void* const* d_in, const int* in_sizes, int n_in,
                              void* d_out, int out_size, void* d_ws, size_t ws_size,
                              hipStream_t stream) {
  const float* xdata = (const float*)d_in[0];
  const float* x = (const float*)d_in[1];
  const float* pos = (const float*)d_in[2];
  const int* ei = (const int*)d_in[3];
  const int* batch = (const int*)d_in[4];
  const float* w1 = (const float*)d_in[5];
  const float* b1 = (const float*)d_in[6];
  const float* w2 = (const float*)d_in[7];
  const float* b2 = (const float*)d_in[8];
  const float* w3 = (const float*)d_in[9];
  const float* b3 = (const float*)d_in[10];
  const float* Wl1 = (const float*)d_in[11];
  const float* Wr1 = (const float*)d_in[12];
  const float* bs1 = (const float*)d_in[13];
  const float* Wl2 = (const float*)d_in[14];
  const float* Wr2 = (const float*)d_in[15];
  const float* bs2 = (const float*)d_in[16];
  const float* Wl3 = (const float*)d_in[17];
  const float* Wr3 = (const float*)d_in[18];
  const float* bs3 = (const float*)d_in[19];
  const float* Wl4 = (const float*)d_in[20];
  const float* Wr4 = (const float*)d_in[21];
  const float* bs4 = (const float*)d_in[22];

  float* x1_out = (float*)d_out;
  float* gout = (float*)d_out + (size_t)NBATCH * IMG;

  char* ws = (char*)d_ws;
  size_t off = 0;
  auto take = [&](size_t bytes) -> char* {
    char* p = ws + off;
    off = (off + bytes + 255) & ~(size_t)255;
    return p;
  };
  float* hbuf1 = (float*)take((size_t)NBATCH * 16 * IMG * 4);  // conv h1 NHWC bf16 / sage h1,h3
  float* hbuf2 = (float*)take((size_t)NBATCH * 16 * IMG * 4);  // conv h2 NHWC bf16 / sage h2
  unsigned short* aggb = (unsigned short*)take((size_t)N_NODES * HID * 2);
  float* gx = (float*)take((size_t)N_NODES * 8 * 4);
  int* row_ptr = (int*)take((size_t)(N_NODES + 1) * 4);
  int* csr = (int*)take((size_t)N_EDGES * 4);
  int* cnt_mat = (int*)take((size_t)NBKT * NB * 4);
  int* rowscan = (int*)take((size_t)NBKT * NB * 4);
  int* row_total = (int*)take((size_t)NBKT * 4);
  int* bucket_data = (int*)take((size_t)N_EDGES * 4);
  float* z = (float*)take((size_t)N_NODES * 4);
  float* zr = (float*)take((size_t)N_NODES * 4);
  unsigned short* Wb2 = (unsigned short*)take((size_t)128 * 256 * 2);
  unsigned short* Wb3 = (unsigned short*)take((size_t)128 * 256 * 2);
  unsigned short* Wc1 = (unsigned short*)take((size_t)12 * 128 * 2);
  unsigned short* Wc2 = (unsigned short*)take((size_t)20 * 128 * 2);
  (void)ws_size;

  unsigned short* h1c = (unsigned short*)hbuf1;
  unsigned short* h2c = (unsigned short*)hbuf2;
  unsigned short* h1 = (unsigned short*)hbuf1;
  unsigned short* h2 = (unsigned short*)hbuf2;
  unsigned short* h3 = (unsigned short*)hbuf1;

  const int nblk_n = (N_NODES + 255) / 256;
  const int nblk_conv = NBATCH * 16;           // 512
  const int nblk_gemm = (N_NODES + 63) / 64;   // 782

  // ---- weight packs (one launch) ----
  hipLaunchKernelGGL(pack_all_kernel, dim3(273), dim3(256), 0, stream, Wl2, Wr2, Wl3, Wr3, w1,
                     w2, Wb2, Wb3, Wc1, Wc2);

  // ---- CNN stack (MFMA, NHWC bf16 intermediates) ----
  hipLaunchKernelGGL(conv1_mfma_kernel, dim3(nblk_conv), dim3(256), 0, stream, xdata, Wc1, b1,
                     h1c);
  hipLaunchKernelGGL(conv2_mfma_kernel, dim3(nblk_conv), dim3(256), 0, stream, h1c, Wc2, b2,
                     h2c);
  hipLaunchKernelGGL(conv3_f32_kernel, dim3(NBATCH * IMG / 256), dim3(256), 0, stream, h2c, w3,
                     b3, x1_out);

  // ---- CSR build (atomic-free counting sort) ----
  hipLaunchKernelGGL(count_kernel, dim3(NB), dim3(256), 0, stream, ei, cnt_mat);
  hipLaunchKernelGGL(scan_rows_kernel, dim3(NBKT), dim3(1024), 0, stream, cnt_mat, rowscan,
                     row_total);
  hipLaunchKernelGGL(scatter2_kernel, dim3(NB), dim3(256), 0, stream, ei, rowscan, row_total,
                     bucket_data);
  hipLaunchKernelGGL(bucketB_kernel, dim3(NBKT), dim3(256), 0, stream, row_total, bucket_data,
                     row_ptr, csr);

  // ---- node features ----
  hipLaunchKernelGGL(gather_gx_kernel, dim3(nblk_n), dim3(256), 0, stream, x, pos, batch,
                     x1_out, gx);

  // ---- layer 1 (fused agg8 + matmul) -> h1 bf16 ----
  hipLaunchKernelGGL(l1_fused_kernel, dim3((N_NODES + 31) / 32), dim3(256), 0, stream, gx,
                     row_ptr, csr, Wl1, Wr1, bs1, h1);

  // ---- layer 2 ----
  hipLaunchKernelGGL(agg128_bf16_kernel, dim3(N_NODES / 4), dim3(256), 0, stream, h1, row_ptr,
                     csr, aggb);
  hipLaunchKernelGGL(sage_gemm_mfma_kernel, dim3(nblk_gemm), dim3(256), 0, stream, aggb, h1,
                     Wb2, bs2, h2, N_NODES, 1);

  // ---- layer 3 ----
  hipLaunchKernelGGL(agg128_bf16_kernel, dim3(N_NODES / 4), dim3(256), 0, stream, h2, row_ptr,
                     csr, aggb);
  hipLaunchKernelGGL(sage_gemm_mfma_kernel, dim3(nblk_gemm), dim3(256), 0, stream, aggb, h2,
                     Wb3, bs3, h3, N_NODES, 1);

  // ---- layer 4 ----
  hipLaunchKernelGGL(zzr_bf16_kernel, dim3(N_NODES / 4), dim3(256), 0, stream, h3, Wl4, Wr4, z,
                     zr);
  hipLaunchKernelGGL(gout_kernel, dim3(nblk_n), dim3(256), 0, stream, z, zr, row_ptr, csr, bs4,
                     gout);
}

// Round 10
// 179.972 us; speedup vs baseline: 1.3292x; 1.1082x over previous
//
#include <hip/hip_runtime.h>

#define N_NODES 50000
#define N_EDGES 800000
#define NBATCH 32
#define HWDIM 128
#define IMG (HWDIM * HWDIM)
#define HID 128
#define NBKT ((N_NODES + 255) / 256)  // 196 buckets of 256 dst nodes
#define NB 625                        // partition blocks
#define EPB 1280                      // edges per partition block
#define LDSP 40  // sage gemm LDS row stride (bf16)

typedef float f32x4 __attribute__((ext_vector_type(4)));
typedef __bf16 bf16x8 __attribute__((ext_vector_type(8)));
typedef unsigned short u16x8 __attribute__((ext_vector_type(8)));

__device__ __forceinline__ unsigned short f2bf(float x) {
  unsigned u = __builtin_bit_cast(unsigned, x);
  u = (u + 0x7FFF + ((u >> 16) & 1)) >> 16;
  return (unsigned short)u;
}
__device__ __forceinline__ float bf2f(unsigned short h) {
  return __builtin_bit_cast(float, (unsigned)h << 16);
}

// ---------------------------------------------------------------------------
// prep kernel: blocks [0,NB) = edge histogram (count); blocks [NB, NB+273) =
// weight packs (Wb2, Wb3, Wc1, Wc2).
// ---------------------------------------------------------------------------
__global__ __launch_bounds__(256) void prep_kernel(
    const int* __restrict__ ei, int* __restrict__ cnt_mat,
    const float* __restrict__ Wl2, const float* __restrict__ Wr2,
    const float* __restrict__ Wl3, const float* __restrict__ Wr3,
    const float* __restrict__ w1, const float* __restrict__ w2,
    unsigned short* __restrict__ Wb2, unsigned short* __restrict__ Wb3,
    unsigned short* __restrict__ Wc1, unsigned short* __restrict__ Wc2) {
  __shared__ int hist[NBKT];
  int t = threadIdx.x;
  if (blockIdx.x < NB) {
    if (t < NBKT) hist[t] = 0;
    __syncthreads();
    int e0 = blockIdx.x * EPB;
#pragma unroll
    for (int i = 0; i < EPB / 256; ++i) {
      int d = ei[N_EDGES + e0 + i * 256 + t];
      atomicAdd(&hist[d >> 8], 1);
    }
    __syncthreads();
    if (t < NBKT) cnt_mat[t * NB + blockIdx.x] = hist[t];
    return;
  }
  int tt = (blockIdx.x - NB) * 256 + t;
  if (tt < 65536) {
    const float* Wl = (tt < 32768) ? Wl2 : Wl3;
    const float* Wr = (tt < 32768) ? Wr2 : Wr3;
    unsigned short* Wb = (tt < 32768) ? Wb2 : Wb3;
    int q = tt & 32767;
    int j = q >> 8, k = q & 255;
    float v = (k < 128) ? Wl[j * 128 + k] : Wr[j * 128 + (k - 128)];
    Wb[q] = f2bf(v);
    return;
  }
  int t2 = tt - 65536;
  const float* w;
  unsigned short* dst;
  int CIN, idx;
  if (t2 < 1536) {
    w = w1; dst = Wc1; CIN = 8; idx = t2;
  } else if (t2 < 1536 + 2560) {
    w = w2; dst = Wc2; CIN = 16; idx = t2 - 1536;
  } else {
    return;
  }
  int j = idx & 7;
  int n = (idx >> 3) & 15;
  int sgi = idx >> 7;
  int k = sgi * 8 + j;
  int tap = k / CIN;
  int ci = k % CIN;
  dst[idx] = (tap < 9) ? f2bf(w[(n * CIN + ci) * 9 + tap]) : (unsigned short)0;
}

// ---------------------------------------------------------------------------
// MFMA conv1: CIN=8 (f32 NCHW input), COUT=16, relu, out NHWC bf16.
// ---------------------------------------------------------------------------
__global__ __launch_bounds__(256) void conv1_mfma_kernel(
    const float* __restrict__ in, const unsigned short* __restrict__ Wc,
    const float* __restrict__ bias, unsigned short* __restrict__ out) {
  __shared__ unsigned short lds[10 * 130 * 8];
  int tid = threadIdx.x;
  int img = blockIdx.x >> 4;
  int y0 = (blockIdx.x & 15) * 8;
  int lane = tid & 63, wave = tid >> 6;
  int l15 = lane & 15, g = lane >> 4;

  const float* sb = in + (size_t)img * 8 * IMG;
#pragma unroll
  for (int i = 0; i < 5; ++i) {
    int idx = tid + i * 256;
    int r = idx >> 7;
    int x = idx & 127;
    int gy = y0 - 1 + r;
    u16x8 v = {};
    if ((unsigned)gy < (unsigned)HWDIM) {
      const float* sp = sb + gy * HWDIM + x;
#pragma unroll
      for (int ci = 0; ci < 8; ++ci) v[ci] = f2bf(sp[ci * IMG]);
    }
    *(u16x8*)&lds[(r * 130 + x + 1) * 8] = v;
  }
  if (tid < 20) {
    int r = tid >> 1, c = (tid & 1) * 129;
    *(u16x8*)&lds[(r * 130 + c) * 8] = (u16x8){};
  }

  bf16x8 bfrag[3];
  int adel[3];
#pragma unroll
  for (int s = 0; s < 3; ++s) {
    bfrag[s] = __builtin_bit_cast(bf16x8, *(const u16x8*)(Wc + (((s * 4 + g) * 16) + l15) * 8));
    int tap = (32 * s + 8 * g) / 8;
    tap = tap > 8 ? 8 : tap;
    adel[s] = ((tap / 3) * 130 + (tap % 3)) * 8;
  }
  float bv = bias[l15];
  __syncthreads();

#pragma unroll
  for (int ti = 0; ti < 16; ++ti) {
    int tile = wave * 16 + ti;
    int ly = tile >> 3, xb = (tile & 7) * 16;
    int tb = (ly * 130 + xb + l15) * 8;
    f32x4 acc = {};
#pragma unroll
    for (int s = 0; s < 3; ++s) {
      bf16x8 a = __builtin_bit_cast(bf16x8, *(const u16x8*)&lds[tb + adel[s]]);
      acc = __builtin_amdgcn_mfma_f32_16x16x32_bf16(a, bfrag[s], acc, 0, 0, 0);
    }
    size_t base = (((size_t)img * HWDIM + y0 + ly) * HWDIM + xb);
#pragma unroll
    for (int r = 0; r < 4; ++r) {
      float v = fmaxf(acc[r] + bv, 0.0f);
      out[(base + g * 4 + r) * 16 + l15] = f2bf(v);
    }
  }
}

// ---------------------------------------------------------------------------
// MFMA conv2: CIN=16 (NHWC bf16 input), COUT=16, relu, out NHWC bf16.
// ---------------------------------------------------------------------------
__global__ __launch_bounds__(256) void conv2_mfma_kernel(
    const unsigned short* __restrict__ in, const unsigned short* __restrict__ Wc,
    const float* __restrict__ bias, unsigned short* __restrict__ out) {
  __shared__ unsigned short lds[10 * 130 * 24];
  int tid = threadIdx.x;
  int img = blockIdx.x >> 4;
  int y0 = (blockIdx.x & 15) * 8;
  int lane = tid & 63, wave = tid >> 6;
  int l15 = lane & 15, g = lane >> 4;

  const unsigned short* sb = in + (size_t)img * IMG * 16;
#pragma unroll
  for (int i = 0; i < 10; ++i) {
    int idx = tid + i * 256;
    int r = idx >> 8;
    int x = (idx & 255) >> 1;
    int hh = idx & 1;
    int gy = y0 - 1 + r;
    u16x8 v = {};
    if ((unsigned)gy < (unsigned)HWDIM) v = *(const u16x8*)(sb + ((size_t)gy * HWDIM + x) * 16 + hh * 8);
    *(u16x8*)&lds[(r * 130 + x + 1) * 24 + hh * 8] = v;
  }
  if (tid < 20) {
    int r = tid >> 1, c = (tid & 1) * 129;
#pragma unroll
    for (int q = 0; q < 3; ++q) *(u16x8*)&lds[(r * 130 + c) * 24 + q * 8] = (u16x8){};
  }

  bf16x8 bfrag[5];
  int adel[5];
#pragma unroll
  for (int s = 0; s < 5; ++s) {
    bfrag[s] = __builtin_bit_cast(bf16x8, *(const u16x8*)(Wc + (((s * 4 + g) * 16) + l15) * 8));
    int tap = (32 * s + 8 * g) / 16;
    tap = tap > 8 ? 8 : tap;
    adel[s] = ((tap / 3) * 130 + (tap % 3)) * 24 + (g & 1) * 8;
  }
  float bv = bias[l15];
  __syncthreads();

#pragma unroll
  for (int ti = 0; ti < 16; ++ti) {
    int tile = wave * 16 + ti;
    int ly = tile >> 3, xb = (tile & 7) * 16;
    int tb = (ly * 130 + xb + l15) * 24;
    f32x4 acc = {};
#pragma unroll
    for (int s = 0; s < 5; ++s) {
      bf16x8 a = __builtin_bit_cast(bf16x8, *(const u16x8*)&lds[tb + adel[s]]);
      acc = __builtin_amdgcn_mfma_f32_16x16x32_bf16(a, bfrag[s], acc, 0, 0, 0);
    }
    size_t base = (((size_t)img * HWDIM + y0 + ly) * HWDIM + xb);
#pragma unroll
    for (int r = 0; r < 4; ++r) {
      float v = fmaxf(acc[r] + bv, 0.0f);
      out[(base + g * 4 + r) * 16 + l15] = f2bf(v);
    }
  }
}

// ---------------------------------------------------------------------------
// conv3: CIN=16 (NHWC bf16), COUT=1, no relu, f32 NCHW out. 1 px/thread.
// ---------------------------------------------------------------------------
__global__ __launch_bounds__(256) void conv3_f32_kernel(const unsigned short* __restrict__ h2,
                                                        const float* __restrict__ w3,
                                                        const float* __restrict__ b3,
                                                        float* __restrict__ x1) {
  __shared__ float w9[9][16];
  __shared__ float b3s;
  int tid = threadIdx.x;
  if (tid < 144) {
    int ci = tid & 15, tap = tid >> 4;
    w9[tap][ci] = w3[ci * 9 + tap];
  }
  if (tid == 144) b3s = b3[0];
  __syncthreads();
  int t = blockIdx.x * 256 + tid;
  int x = t & 127;
  int y = (t >> 7) & 127;
  int img = t >> 14;
  float acc = b3s;
#pragma unroll
  for (int dy = 0; dy < 3; ++dy) {
    int yy = y + dy - 1;
    if ((unsigned)yy >= (unsigned)HWDIM) continue;
#pragma unroll
    for (int dx = 0; dx < 3; ++dx) {
      int xx = x + dx - 1;
      if ((unsigned)xx >= (unsigned)HWDIM) continue;
      const u16x8* p = (const u16x8*)(h2 + (((size_t)img * HWDIM + yy) * HWDIM + xx) * 16);
      u16x8 lo = p[0], hi = p[1];
      const float* wt = w9[dy * 3 + dx];
#pragma unroll
      for (int j = 0; j < 8; ++j) acc += bf2f(lo[j]) * wt[j];
#pragma unroll
      for (int j = 0; j < 8; ++j) acc += bf2f(hi[j]) * wt[8 + j];
    }
  }
  x1[(size_t)img * IMG + y * HWDIM + x] = acc;
}

// ---------------------------------------------------------------------------
__global__ __launch_bounds__(1024) void scan_rows_kernel(const int* __restrict__ cnt_mat,
                                                         int* __restrict__ rowscan,
                                                         int* __restrict__ row_total) {
  __shared__ int wsum[16];
  int row = blockIdx.x;
  int t = threadIdx.x;
  int lane = t & 63, w = t >> 6;
  int v = (t < NB) ? cnt_mat[row * NB + t] : 0;
  int s = v;
#pragma unroll
  for (int off = 1; off < 64; off <<= 1) {
    int u = __shfl_up(s, off, 64);
    if (lane >= off) s += u;
  }
  if (lane == 63) wsum[w] = s;
  __syncthreads();
  if (w == 0 && lane < 16) {
    int ws = wsum[lane];
#pragma unroll
    for (int off = 1; off < 16; off <<= 1) {
      int u = __shfl_up(ws, off, 64);
      if (lane >= off) ws += u;
    }
    wsum[lane] = ws;
  }
  __syncthreads();
  int base = (w > 0) ? wsum[w - 1] : 0;
  int incl = s + base;
  if (t < NB) rowscan[row * NB + t] = incl - v;
  if (t == NB - 1) row_total[row] = incl;
}

// helper: block-wide exclusive scan of row_total[0..NBKT) into bb[] (256 thr)
__device__ __forceinline__ void scan_bases(const int* __restrict__ row_total, int* bb,
                                           int* wsum) {
  int t = threadIdx.x;
  int lane = t & 63, w = t >> 6;
  int v = (t < NBKT) ? row_total[t] : 0;
  int s = v;
#pragma unroll
  for (int off = 1; off < 64; off <<= 1) {
    int u = __shfl_up(s, off, 64);
    if (lane >= off) s += u;
  }
  if (lane == 63) wsum[w] = s;
  __syncthreads();
  int add = 0;
#pragma unroll
  for (int i = 0; i < 4; ++i)
    if (i < w) add += wsum[i];
  if (t < NBKT) bb[t] = s + add - v;
  __syncthreads();
}

__global__ __launch_bounds__(256) void scatter2_kernel(const int* __restrict__ ei,
                                                       const int* __restrict__ rowscan,
                                                       const int* __restrict__ row_total,
                                                       int* __restrict__ bucket_data) {
  __shared__ int bb[NBKT];
  __shared__ int lhist[NBKT];
  __shared__ int lexcl[NBKT];
  __shared__ int gb[NBKT];
  __shared__ int wsum[4];
  __shared__ int lds_pack[EPB];
  __shared__ int lds_dest[EPB];
  int t = threadIdx.x;
  int blk = blockIdx.x;
  scan_bases(row_total, bb, wsum);
  if (t < NBKT) lhist[t] = 0;
  __syncthreads();
  int e0 = blk * EPB;
  int myb[EPB / 256], myp[EPB / 256], mypack[EPB / 256];
#pragma unroll
  for (int i = 0; i < EPB / 256; ++i) {
    int e = e0 + i * 256 + t;
    int s = ei[e];
    int d = ei[N_EDGES + e];
    int b = d >> 8;
    myb[i] = b;
    mypack[i] = s | ((d & 255) << 16);
    myp[i] = atomicAdd(&lhist[b], 1);
  }
  __syncthreads();
  {
    int lane = t & 63, w = t >> 6;
    int v = (t < NBKT) ? lhist[t] : 0;
    int s = v;
#pragma unroll
    for (int off = 1; off < 64; off <<= 1) {
      int u = __shfl_up(s, off, 64);
      if (lane >= off) s += u;
    }
    if (lane == 63) wsum[w] = s;
    __syncthreads();
    int add = 0;
#pragma unroll
    for (int i = 0; i < 4; ++i)
      if (i < w) add += wsum[i];
    if (t < NBKT) {
      lexcl[t] = s + add - v;
      gb[t] = bb[t] + rowscan[t * NB + blk];
    }
  }
  __syncthreads();
#pragma unroll
  for (int i = 0; i < EPB / 256; ++i) {
    int slot = lexcl[myb[i]] + myp[i];
    lds_pack[slot] = mypack[i];
    lds_dest[slot] = gb[myb[i]] + myp[i];
  }
  __syncthreads();
#pragma unroll
  for (int i = 0; i < EPB / 256; ++i) {
    int slot = i * 256 + t;
    bucket_data[lds_dest[slot]] = lds_pack[slot];
  }
}

// ---------------------------------------------------------------------------
// bucketB + fused gather_gx (same 196-block grid, independent inputs)
// ---------------------------------------------------------------------------
__global__ __launch_bounds__(256) void bucketB_kernel(
    const int* __restrict__ row_total, const int* __restrict__ bucket_data,
    int* __restrict__ row_ptr, int* __restrict__ csr,
    const float* __restrict__ x, const float* __restrict__ pos,
    const int* __restrict__ batch, const float* __restrict__ x1,
    float* __restrict__ gx) {
  __shared__ int bb[NBKT];
  __shared__ int cnts[256];
  __shared__ int curs[256];
  __shared__ int wsum[4];
  int b = blockIdx.x;
  int t = threadIdx.x;
  // ---- fused gather_gx ----
  {
    int i = b * 256 + t;
    if (i < N_NODES) {
      float px = pos[2 * i + 0];
      float py = pos[2 * i + 1];
      int cx = (int)rintf(px / 20.0f * 127.0f);
      int cy = (int)rintf(py / 20.0f * 127.0f);
      cx = min(max(cx, 0), HWDIM - 1);
      cy = min(max(cy, 0), HWDIM - 1);
      int bi = batch[i];
      float cn = x1[(size_t)bi * IMG + cy * HWDIM + cx];
      const float* xr = x + (size_t)i * 8;
      float* g = gx + (size_t)i * 8;
      g[0] = xr[0];
      g[1] = xr[1];
      g[2] = xr[5];
      g[3] = xr[6];
      g[4] = xr[7];
      g[5] = px;
      g[6] = py;
      g[7] = cn;
    }
  }
  // ---- bucketB proper ----
  scan_bases(row_total, bb, wsum);
  int cnt = row_total[b];
  int base = bb[b];
  if (b == 0 && t == 0) row_ptr[N_NODES] = N_EDGES;
  cnts[t] = 0;
  __syncthreads();
  const int* bd = bucket_data + base;
  for (int k = t; k < cnt; k += 256) {
    int v = bd[k];
    atomicAdd(&cnts[(v >> 16) & 255], 1);
  }
  __syncthreads();
  int v = cnts[t];
  int lane = t & 63, w = t >> 6;
  int s = v;
#pragma unroll
  for (int off = 1; off < 64; off <<= 1) {
    int u = __shfl_up(s, off, 64);
    if (lane >= off) s += u;
  }
  if (lane == 63) wsum[w] = s;
  __syncthreads();
  int add = 0;
#pragma unroll
  for (int i = 0; i < 4; ++i)
    if (i < w) add += wsum[i];
  int excl = s + add - v;
  int node = b * 256 + t;
  if (node < N_NODES) row_ptr[node] = base + excl;
  curs[t] = excl;
  __syncthreads();
  for (int k = t; k < cnt; k += 256) {
    int vv = bd[k];
    int p = atomicAdd(&curs[(vv >> 16) & 255], 1);
    csr[base + p] = vv & 0xffff;
  }
}

// ---------------------------------------------------------------------------
// Fused layer 1: agg8 (CSR mean of gx) + [agg,gx] @ [Wl1;Wr1] + bias, relu.
// ---------------------------------------------------------------------------
__global__ __launch_bounds__(256) void l1_fused_kernel(
    const float* __restrict__ gx, const int* __restrict__ row_ptr,
    const int* __restrict__ csr, const float* __restrict__ Wl,
    const float* __restrict__ Wr, const float* __restrict__ b,
    unsigned short* __restrict__ out) {
  __shared__ float wl[8][128];
  __shared__ float wr[8][128];
  __shared__ float aggs[32][8];
  int tid = threadIdx.x;
  for (int t = tid; t < 1024; t += 256) {
    int j = t >> 3, k = t & 7;
    wl[k][j] = Wl[t];
    wr[k][j] = Wr[t];
  }
  int node0 = blockIdx.x * 32;
  {
    int i = node0 + (tid >> 3);
    int f = tid & 7;
    float acc = 0.0f;
    if (i < N_NODES) {
      int beg = row_ptr[i], end = row_ptr[i + 1];
      int k = beg;
      for (; k + 2 <= end; k += 2) {
        int s0 = csr[k], s1 = csr[k + 1];
        acc += gx[(size_t)s0 * 8 + f] + gx[(size_t)s1 * 8 + f];
      }
      for (; k < end; ++k) acc += gx[(size_t)csr[k] * 8 + f];
      acc /= fmaxf((float)(end - beg), 1.0f);
    }
    aggs[tid >> 3][f] = acc;
  }
  __syncthreads();
  int nl = tid >> 3;
  int i = node0 + nl;
  if (i >= N_NODES) return;
  float av[8], gv[8];
#pragma unroll
  for (int k = 0; k < 8; ++k) {
    av[k] = aggs[nl][k];
    gv[k] = gx[(size_t)i * 8 + k];
  }
  int c0 = (tid & 7) * 16;
#pragma unroll
  for (int c = 0; c < 16; ++c) {
    int col = c0 + c;
    float acc = b[col];
#pragma unroll
    for (int k = 0; k < 8; ++k) acc += av[k] * wl[k][col] + gv[k] * wr[k][col];
    out[(size_t)i * HID + col] = f2bf(fmaxf(acc, 0.0f));
  }
}

// ---------------------------------------------------------------------------
// CSR aggregation, C=128, bf16 in/out, f32 accum. One wave/node.
// ---------------------------------------------------------------------------
__global__ __launch_bounds__(256) void agg128_bf16_kernel(
    const unsigned short* __restrict__ h, const int* __restrict__ row_ptr,
    const int* __restrict__ csr, unsigned short* __restrict__ out) {
  int wid = (blockIdx.x * blockDim.x + threadIdx.x) >> 6;
  int lane = threadIdx.x & 63;
  if (wid >= N_NODES) return;
  int beg = __builtin_amdgcn_readfirstlane(row_ptr[wid]);
  int end = __builtin_amdgcn_readfirstlane(row_ptr[wid + 1]);
  float ax = 0.0f, ay = 0.0f;
  const unsigned short* hp = h + 2 * lane;
  int k = beg;
  for (; k + 4 <= end; k += 4) {
    int s0 = csr[k];
    int s1 = csr[k + 1];
    int s2 = csr[k + 2];
    int s3 = csr[k + 3];
    unsigned v0 = *(const unsigned*)(hp + (size_t)s0 * HID);
    unsigned v1 = *(const unsigned*)(hp + (size_t)s1 * HID);
    unsigned v2 = *(const unsigned*)(hp + (size_t)s2 * HID);
    unsigned v3 = *(const unsigned*)(hp + (size_t)s3 * HID);
    ax += (bf2f(v0 & 0xffff) + bf2f(v1 & 0xffff)) + (bf2f(v2 & 0xffff) + bf2f(v3 & 0xffff));
    ay += (bf2f(v0 >> 16) + bf2f(v1 >> 16)) + (bf2f(v2 >> 16) + bf2f(v3 >> 16));
  }
  for (; k < end; ++k) {
    int s = csr[k];
    unsigned v = *(const unsigned*)(hp + (size_t)s * HID);
    ax += bf2f(v & 0xffff);
    ay += bf2f(v >> 16);
  }
  float inv = 1.0f / fmaxf((float)(end - beg), 1.0f);
  unsigned o = (unsigned)f2bf(ax * inv) | ((unsigned)f2bf(ay * inv) << 16);
  *(unsigned*)(out + (size_t)wid * HID + 2 * lane) = o;
}

// ---------------------------------------------------------------------------
// MFMA SAGE GEMM: bf16 in, f32 accum, bf16 out. BM=64, BN=128, BK=32.
// Optional fused z/zr projection (layer-4 GEMV) in the epilogue.
// ---------------------------------------------------------------------------
__global__ __launch_bounds__(256) void sage_gemm_mfma_kernel(
    const unsigned short* __restrict__ A1, const unsigned short* __restrict__ A2,
    const unsigned short* __restrict__ Wb, const float* __restrict__ bias,
    unsigned short* __restrict__ C, int M, int do_relu,
    const float* __restrict__ Wl4, const float* __restrict__ Wr4,
    float* __restrict__ z, float* __restrict__ zr, int do_zzr) {
  __shared__ unsigned short Alds[64 * LDSP];
  __shared__ unsigned short Wlds[128 * LDSP];
  int tid = threadIdx.x;
  int wave = tid >> 6, lane = tid & 63;
  int l15 = lane & 15, g = lane >> 4;
  int row0 = blockIdx.x * 64;

  f32x4 acc[8];
#pragma unroll
  for (int n = 0; n < 8; ++n) acc[n] = (f32x4){0.f, 0.f, 0.f, 0.f};

  for (int ks = 0; ks < 8; ++ks) {
    const unsigned short* Asrc = (ks < 4) ? A1 : A2;
    int k0 = (ks & 3) * 32;
    {
      int r = tid >> 2, cc = tid & 3;  // 64 rows x 4 chunks
      int gr = row0 + r;
      u16x8 v = {};
      if (gr < M) v = *(const u16x8*)(Asrc + (size_t)gr * HID + k0 + cc * 8);
      *(u16x8*)(&Alds[r * LDSP + cc * 8]) = v;
    }
#pragma unroll
    for (int it = 0; it < 2; ++it) {
      int c = tid + it * 256;
      int j = c >> 2, cc = c & 3;
      u16x8 wv = *(const u16x8*)(Wb + j * 256 + ks * 32 + cc * 8);
      *(u16x8*)(&Wlds[j * LDSP + cc * 8]) = wv;
    }
    __syncthreads();

    bf16x8 a = __builtin_bit_cast(bf16x8, *(const u16x8*)(&Alds[(wave * 16 + l15) * LDSP + g * 8]));
#pragma unroll
    for (int n = 0; n < 8; ++n) {
      bf16x8 w = __builtin_bit_cast(bf16x8, *(const u16x8*)(&Wlds[(16 * n + l15) * LDSP + g * 8]));
      acc[n] = __builtin_amdgcn_mfma_f32_16x16x32_bf16(a, w, acc[n], 0, 0, 0);
    }
    __syncthreads();
  }

  float wl4v[8], wr4v[8];
  if (do_zzr) {
#pragma unroll
    for (int n = 0; n < 8; ++n) {
      wl4v[n] = Wl4[16 * n + l15];
      wr4v[n] = Wr4[16 * n + l15];
    }
  }
  float zp[4] = {0.f, 0.f, 0.f, 0.f};
  float zrp[4] = {0.f, 0.f, 0.f, 0.f};

#pragma unroll
  for (int n = 0; n < 8; ++n) {
    int col = 16 * n + l15;
    float bv = bias[col];
#pragma unroll
    for (int r = 0; r < 4; ++r) {
      int grow = row0 + wave * 16 + g * 4 + r;
      float v = acc[n][r] + bv;
      if (do_relu) v = fmaxf(v, 0.0f);
      if (grow < M) C[(size_t)grow * HID + col] = f2bf(v);
      if (do_zzr) {
        zp[r] += v * wl4v[n];
        zrp[r] += v * wr4v[n];
      }
    }
  }
  if (do_zzr) {
#pragma unroll
    for (int r = 0; r < 4; ++r) {
      float a = zp[r], c = zrp[r];
#pragma unroll
      for (int off = 1; off < 16; off <<= 1) {
        a += __shfl_xor(a, off, 64);
        c += __shfl_xor(c, off, 64);
      }
      int grow = row0 + wave * 16 + g * 4 + r;
      if (l15 == 0 && grow < M) {
        z[grow] = a;
        zr[grow] = c;
      }
    }
  }
}

// ---------------------------------------------------------------------------
__global__ void gout_kernel(const float* __restrict__ z, const float* __restrict__ zr,
                            const int* __restrict__ row_ptr, const int* __restrict__ csr,
                            const float* __restrict__ bs4, float* __restrict__ gout) {
  int i = blockIdx.x * blockDim.x + threadIdx.x;
  if (i >= N_NODES) return;
  int beg = row_ptr[i], end = row_ptr[i + 1];
  float s = 0.0f;
  int k = beg;
  for (; k + 2 <= end; k += 2) s += z[csr[k]] + z[csr[k + 1]];
  for (; k < end; ++k) s += z[csr[k]];
  float d = fmaxf((float)(end - beg), 1.0f);
  gout[i] = s / d + zr[i] + bs4[0];
}

// ---------------------------------------------------------------------------
extern "C" void kernel_launch(void* const* d_in, const int* in_sizes, int n_in,
                              void* d_out, int out_size, void* d_ws, size_t ws_size,
                              hipStream_t stream) {
  const float* xdata = (const float*)d_in[0];
  const float* x = (const float*)d_in[1];
  const float* pos = (const float*)d_in[2];
  const int* ei = (const int*)d_in[3];
  const int* batch = (const int*)d_in[4];
  const float* w1 = (const float*)d_in[5];
  const float* b1 = (const float*)d_in[6];
  const float* w2 = (const float*)d_in[7];
  const float* b2 = (const float*)d_in[8];
  const float* w3 = (const float*)d_in[9];
  const float* b3 = (const float*)d_in[10];
  const float* Wl1 = (const float*)d_in[11];
  const float* Wr1 = (const float*)d_in[12];
  const float* bs1 = (const float*)d_in[13];
  const float* Wl2 = (const float*)d_in[14];
  const float* Wr2 = (const float*)d_in[15];
  const float* bs2 = (const float*)d_in[16];
  const float* Wl3 = (const float*)d_in[17];
  const float* Wr3 = (const float*)d_in[18];
  const float* bs3 = (const float*)d_in[19];
  const float* Wl4 = (const float*)d_in[20];
  const float* Wr4 = (const float*)d_in[21];
  const float* bs4 = (const float*)d_in[22];

  float* x1_out = (float*)d_out;
  float* gout = (float*)d_out + (size_t)NBATCH * IMG;

  char* ws = (char*)d_ws;
  size_t off = 0;
  auto take = [&](size_t bytes) -> char* {
    char* p = ws + off;
    off = (off + bytes + 255) & ~(size_t)255;
    return p;
  };
  float* hbuf1 = (float*)take((size_t)NBATCH * 16 * IMG * 4);  // conv h1 NHWC bf16 / sage h1,h3
  float* hbuf2 = (float*)take((size_t)NBATCH * 16 * IMG * 4);  // conv h2 NHWC bf16 / sage h2
  unsigned short* aggb = (unsigned short*)take((size_t)N_NODES * HID * 2);
  float* gx = (float*)take((size_t)N_NODES * 8 * 4);
  int* row_ptr = (int*)take((size_t)(N_NODES + 1) * 4);
  int* csr = (int*)take((size_t)N_EDGES * 4);
  int* cnt_mat = (int*)take((size_t)NBKT * NB * 4);
  int* rowscan = (int*)take((size_t)NBKT * NB * 4);
  int* row_total = (int*)take((size_t)NBKT * 4);
  int* bucket_data = (int*)take((size_t)N_EDGES * 4);
  float* z = (float*)take((size_t)N_NODES * 4);
  float* zr = (float*)take((size_t)N_NODES * 4);
  unsigned short* Wb2 = (unsigned short*)take((size_t)128 * 256 * 2);
  unsigned short* Wb3 = (unsigned short*)take((size_t)128 * 256 * 2);
  unsigned short* Wc1 = (unsigned short*)take((size_t)12 * 128 * 2);
  unsigned short* Wc2 = (unsigned short*)take((size_t)20 * 128 * 2);
  (void)ws_size;

  unsigned short* h1c = (unsigned short*)hbuf1;
  unsigned short* h2c = (unsigned short*)hbuf2;
  unsigned short* h1 = (unsigned short*)hbuf1;
  unsigned short* h2 = (unsigned short*)hbuf2;
  unsigned short* h3 = (unsigned short*)hbuf1;

  const int nblk_n = (N_NODES + 255) / 256;
  const int nblk_conv = NBATCH * 16;          // 512
  const int nblk_gemm = (N_NODES + 63) / 64;  // 782

  // ---- prep: edge histogram + weight packs (one launch) ----
  hipLaunchKernelGGL(prep_kernel, dim3(NB + 273), dim3(256), 0, stream, ei, cnt_mat, Wl2, Wr2,
                     Wl3, Wr3, w1, w2, Wb2, Wb3, Wc1, Wc2);

  // ---- CNN stack (MFMA, NHWC bf16 intermediates) ----
  hipLaunchKernelGGL(conv1_mfma_kernel, dim3(nblk_conv), dim3(256), 0, stream, xdata, Wc1, b1,
                     h1c);
  hipLaunchKernelGGL(conv2_mfma_kernel, dim3(nblk_conv), dim3(256), 0, stream, h1c, Wc2, b2,
                     h2c);
  hipLaunchKernelGGL(conv3_f32_kernel, dim3(NBATCH * IMG / 256), dim3(256), 0, stream, h2c, w3,
                     b3, x1_out);

  // ---- CSR build ----
  hipLaunchKernelGGL(scan_rows_kernel, dim3(NBKT), dim3(1024), 0, stream, cnt_mat, rowscan,
                     row_total);
  hipLaunchKernelGGL(scatter2_kernel, dim3(NB), dim3(256), 0, stream, ei, rowscan, row_total,
                     bucket_data);
  hipLaunchKernelGGL(bucketB_kernel, dim3(NBKT), dim3(256), 0, stream, row_total, bucket_data,
                     row_ptr, csr, x, pos, batch, x1_out, gx);

  // ---- layer 1 (fused agg8 + matmul) -> h1 bf16 ----
  hipLaunchKernelGGL(l1_fused_kernel, dim3((N_NODES + 31) / 32), dim3(256), 0, stream, gx,
                     row_ptr, csr, Wl1, Wr1, bs1, h1);

  // ---- layer 2 ----
  hipLaunchKernelGGL(agg128_bf16_kernel, dim3(N_NODES / 4), dim3(256), 0, stream, h1, row_ptr,
                     csr, aggb);
  hipLaunchKernelGGL(sage_gemm_mfma_kernel, dim3(nblk_gemm), dim3(256), 0, stream, aggb, h1,
                     Wb2, bs2, h2, N_NODES, 1, (const float*)nullptr, (const float*)nullptr,
                     (float*)nullptr, (float*)nullptr, 0);

  // ---- layer 3 (+ fused z/zr projection) ----
  hipLaunchKernelGGL(agg128_bf16_kernel, dim3(N_NODES / 4), dim3(256), 0, stream, h2, row_ptr,
                     csr, aggb);
  hipLaunchKernelGGL(sage_gemm_mfma_kernel, dim3(nblk_gemm), dim3(256), 0, stream, aggb, h2,
                     Wb3, bs3, h3, N_NODES, 1, Wl4, Wr4, z, zr, 1);

  // ---- layer 4 aggregate ----
  hipLaunchKernelGGL(gout_kernel, dim3(nblk_n), dim3(256), 0, stream, z, zr, row_ptr, csr, bs4,
                     gout);
}